// Round 19
// baseline (312.989 us; speedup 1.0000x reference)
//
#include <hip/hip_runtime.h>
#include <hip/hip_bf16.h>
#include <hip/hip_cooperative_groups.h>

namespace cg = cooperative_groups;

#define N_PTS 16384
#define DIMF  128
#define KNB   16
#define GRES  8
#define NCELL (GRES*GRES*GRES)

typedef __attribute__((ext_vector_type(8))) short bf16x8;
typedef __attribute__((ext_vector_type(4))) short bf16x4;
typedef __attribute__((ext_vector_type(4))) float f32x4;
typedef __attribute__((ext_vector_type(4))) unsigned int u32x4;
typedef __attribute__((ext_vector_type(2))) unsigned int u32x2;

__device__ __forceinline__ unsigned short f2b(float f){
  unsigned int u = __float_as_uint(f);
  u = u + 0x7fffu + ((u >> 16) & 1u);
  return (unsigned short)(u >> 16);
}
// packed RNE f32x2 -> bf16x2 (bit-identical to f2b pairs); no builtin on gfx950 -> inline asm
__device__ __forceinline__ unsigned cvtpk(float lo, float hi){
  unsigned r;
  asm("v_cvt_pk_bf16_f32 %0, %1, %2" : "=v"(r) : "v"(lo), "v"(hi));
  return r;
}
__device__ __forceinline__ float b2f(unsigned short u){
  return __uint_as_float(((unsigned)u) << 16);
}
__device__ __forceinline__ float b2fs(short s){
  return __uint_as_float(((unsigned)(unsigned short)s) << 16);
}
__device__ __forceinline__ float unsort_f(unsigned s){
  unsigned u = (s & 0x80000000u) ? (s ^ 0x80000000u) : ~s;
  return __uint_as_float(u);
}

// ---------------- cooperative build: zero -> count||pack -> scan -> scatter ----------------
// Replaces 4 dependent dispatches with one cooperative kernel (512 blocks x 256 thr).
// Pack (blocks 64-511) is chain-independent and runs during the count phase.
__global__ __launch_bounds__(256) void build_coop(const float* __restrict__ pos,
                                                  int* __restrict__ cnt, int* __restrict__ starts, int* __restrict__ fillp,
                                                  float4* __restrict__ pos4, int* __restrict__ pidx, int* __restrict__ inv,
                                                  const float* __restrict__ w0, const float* __restrict__ w1,
                                                  const float* __restrict__ w2, const float* __restrict__ w3,
                                                  const float* __restrict__ w4, const float* __restrict__ w5,
                                                  const float* __restrict__ w6,
                                                  short* __restrict__ dst){
  cg::grid_group grid = cg::this_grid();
  int b = blockIdx.x, t = threadIdx.x;

  // phase 1: zero cell counters (block 0)
  if (b == 0){ cnt[2*t] = 0; cnt[2*t+1] = 0; }
  grid.sync();

  // phase 2: count (blocks 0-63) || weight pack (blocks 64-511)
  if (b < 64){
    int i = b*256 + t;
    float px = pos[i*3+0], py = pos[i*3+1], pz = pos[i*3+2];
    int cx = min(GRES-1, max(0,(int)(px*(float)GRES)));
    int cy = min(GRES-1, max(0,(int)(py*(float)GRES)));
    int cz = min(GRES-1, max(0,(int)(pz*(float)GRES)));
    atomicAdd(&cnt[(cz*GRES+cy)*GRES+cx], 1);
  } else {
    int pb = b - 64;
    int slot = pb >> 6;                         // 64 blocks per weight
    const float* src = (slot==0)?w0:(slot==1)?w1:(slot==2)?w2:(slot==3)?w3:(slot==4)?w4:(slot==5)?w5:w6;
    int f = (pb & 63)*256 + t;                  // 0..16383
    int j  = f & 7;
    int ln = (f >> 3) & 63;
    int ks = (f >> 9) & 3;
    int nt = f >> 11;
    int k = ks*32 + ((ln >> 4) << 3) + j;
    int n = nt*16 + (ln & 15);
    dst[slot*16384 + f] = (short)f2b(src[k*DIMF + n]);
  }
  grid.sync();

  // phase 3: exclusive scan of 512 counts (block 0; wave shfl prefix)
  if (b == 0){
    __shared__ int wsum[4];
    int lane = t & 63, w = t >> 6;
    int a = cnt[2*t], bb = cnt[2*t+1];
    int s = a + bb;
    int p = s;
    #pragma unroll
    for (int off = 1; off < 64; off <<= 1){
      int v = __shfl_up(p, off, 64);
      if (lane >= off) p += v;
    }
    if (lane == 63) wsum[w] = p;
    __syncthreads();
    int base = 0;
    for (int i = 0; i < w; ++i) base += wsum[i];
    int excl = base + p - s;
    starts[2*t]   = excl;      fillp[2*t]   = excl;
    starts[2*t+1] = excl + a;  fillp[2*t+1] = excl + a;
  }
  grid.sync();

  // phase 4: scatter (blocks 0-63); sq numpy-style ((x*x+y*y)+z*z) separate f32 roundings
  if (b < 64){
    int i = b*256 + t;
    float px = pos[i*3+0], py = pos[i*3+1], pz = pos[i*3+2];
    int cx = min(GRES-1, max(0,(int)(px*(float)GRES)));
    int cy = min(GRES-1, max(0,(int)(py*(float)GRES)));
    int cz = min(GRES-1, max(0,(int)(pz*(float)GRES)));
    int c = (cz*GRES+cy)*GRES+cx;
    float sq = __fadd_rn(__fadd_rn(__fmul_rn(px,px), __fmul_rn(py,py)), __fmul_rn(pz,pz));
    int s = atomicAdd(&fillp[c], 1);
    pos4[s] = make_float4(px, py, pz, sq);
    pidx[s] = i;
    inv[i] = s;
  }
}

// One wave per point. Exact top-16 by (d2, idx); d2 replicates numpy f32 bit-exactly.
// tau^2 threshold filter (exact when admitted>=16) + f64 cell-box pruning (cannot change the
// admitted set) -> ballot-compact -> 64-key bitonic. Rare bound failures: inline exact fallback.
__global__ __launch_bounds__(256) void knn_query64(const float4* __restrict__ pos4, const int* __restrict__ pidx,
                                                   const int* __restrict__ starts, const int* __restrict__ cnt,
                                                   const int* __restrict__ inv,
                                                   int* __restrict__ ind_slot){
  __shared__ unsigned long long cand[4][64];
  int lane = threadIdx.x & 63;
  int wv   = threadIdx.x >> 6;
  int t = blockIdx.x*4 + wv;
  float4 qp = pos4[t];
  float qx = qp.x, qy = qp.y, qz = qp.z, qsq = qp.w;
  int cx = min(GRES-1, max(0,(int)(qx*(float)GRES)));
  int cy = min(GRES-1, max(0,(int)(qy*(float)GRES)));
  int cz = min(GRES-1, max(0,(int)(qz*(float)GRES)));
  int zlo = max(0,cz-1), zhi = min(GRES-1,cz+1);
  int ylo = max(0,cy-1), yhi = min(GRES-1,cy+1);
  int xlo = max(0,cx-1), xhi = min(GRES-1,cx+1);
  const double h = 0.125;
  double dqx=(double)qx, dqy=(double)qy, dqz=(double)qz;

  int nb = 0;
  if (lane < 27){
    int dz = lane/9 - 1, dy = (lane/3)%3 - 1, dx = lane%3 - 1;
    int zz = cz+dz, yy = cy+dy, xx = cx+dx;
    if (zz>=zlo && zz<=zhi && yy>=ylo && yy<=yhi && xx>=xlo && xx<=xhi)
      nb = cnt[(zz*GRES+yy)*GRES+xx];
  }
  #pragma unroll
  for (int o=1;o<64;o<<=1) nb += __shfl_xor(nb, o, 64);
  float V = (float)((zhi-zlo+1)*(yhi-ylo+1)*(xhi-xlo+1)) * 0.001953125f;
  float r3 = 3.8197186f * V / (float)nb;
  float tau2 = 2.0f * __powf(r3, 0.66666667f);

  int nfound = 0;
  bool okscan = false;
  for (int it = 0; it < 8; ++it){
    nfound = 0;
    for (int zz=zlo; zz<=zhi; ++zz)
    for (int yy=ylo; yy<=yhi; ++yy)
    for (int xx=xlo; xx<=xhi; ++xx){
      double mdx = fmax(0.0, fmax((double)xx*h - dqx, dqx - (double)(xx+1)*h));
      double mdy = fmax(0.0, fmax((double)yy*h - dqy, dqy - (double)(yy+1)*h));
      double mdz = fmax(0.0, fmax((double)zz*h - dqz, dqz - (double)(zz+1)*h));
      double md2 = mdx*mdx + mdy*mdy + mdz*mdz;
      if (md2 > (double)tau2 + 1.0e-5) continue;
      int c = (zz*GRES+yy)*GRES+xx;
      int s0 = starts[c], n = cnt[c];
      for (int b = 0; b < n; b += 64){
        int o = b + lane;
        bool valid = o < n;
        float d = 3.0e38f; int idx = 0;
        if (valid){
          float4 pc = pos4[s0+o];
          idx = pidx[s0+o];
          float dot = __fmaf_rn(qz, pc.z, __fmaf_rn(qy, pc.y, __fmul_rn(qx, pc.x)));
          d   = __fsub_rn(__fadd_rn(qsq, pc.w), __fmul_rn(2.0f, dot));
        }
        bool admit = valid && (d < tau2);
        unsigned long long mask = __ballot(admit);
        if (admit){
          int pos = nfound + (int)__popcll(mask & ((1ull<<lane)-1ull));
          if (pos < 64){
            unsigned su = __float_as_uint(d);
            su ^= (unsigned)((int)su >> 31) | 0x80000000u;
            cand[wv][pos] = ((unsigned long long)su << 32) | (unsigned)idx;
          }
        }
        nfound += (int)__popcll(mask);
      }
    }
    if (nfound > 64){ tau2 *= 0.7f; continue; }
    if (nfound < 16){ tau2 *= 2.0f; continue; }
    okscan = true; break;
  }

  bool needfb = !okscan;
  if (okscan){
    asm volatile("s_waitcnt lgkmcnt(0)" ::: "memory");
    __builtin_amdgcn_sched_barrier(0);
    unsigned long long key = (lane < nfound) ? cand[wv][lane] : ~0ull;

    #pragma unroll
    for (int k = 2; k <= 64; k <<= 1){
      #pragma unroll
      for (int j = k>>1; j >= 1; j >>= 1){
        unsigned long long other = __shfl_xor(key, j, 64);
        bool takeSmall = (((lane & k) == 0) != ((lane & j) != 0));
        bool less = other < key;
        key = (takeSmall == less) ? other : key;
      }
    }
    if (lane < 16) ind_slot[t*KNB + lane] = inv[(int)(unsigned)(key & 0xffffffffu)];

    unsigned long long k15 = __shfl(key, 15, 64);
    float b16 = unsort_f((unsigned)(k15 >> 32));
    double mg = 1.0e300;
    if (cx-1 > 0)      mg = fmin(mg, dqx - (double)(cx-1)*h);
    if (cx+1 < GRES-1) mg = fmin(mg, (double)(cx+2)*h - dqx);
    if (cy-1 > 0)      mg = fmin(mg, dqy - (double)(cy-1)*h);
    if (cy+1 < GRES-1) mg = fmin(mg, (double)(cy+2)*h - dqy);
    if (cz-1 > 0)      mg = fmin(mg, dqz - (double)(cz-1)*h);
    if (cz+1 < GRES-1) mg = fmin(mg, (double)(cz+2)*h - dqz);
    needfb = !(mg*mg > (double)b16 + 1.0e-5);
  }

  if (needfb){
    float bd[KNB]; int bi[KNB];
    #pragma unroll
    for (int k=0;k<KNB;++k){ bd[k] = 3.0e38f; bi[k] = 0x7fffffff; }
    for (int r = 0; r < GRES; ++r){
      int zl = max(0, cz-r), zh = min(GRES-1, cz+r);
      int yl = max(0, cy-r), yh = min(GRES-1, cy+r);
      int xl = max(0, cx-r), xh = min(GRES-1, cx+r);
      for (int zz = zl; zz <= zh; ++zz)
      for (int yy = yl; yy <= yh; ++yy)
      for (int xx = xl; xx <= xh; ++xx){
        int ring = max(abs(zz-cz), max(abs(yy-cy), abs(xx-cx)));
        if (ring != r) continue;
        int c = (zz*GRES+yy)*GRES+xx;
        int s0 = starts[c], e = s0 + cnt[c];
        for (int s = s0; s < e; ++s){
          float4 pc = pos4[s];
          int idx = pidx[s];
          float dot = __fmaf_rn(qz, pc.z, __fmaf_rn(qy, pc.y, __fmul_rn(qx, pc.x)));
          float d   = __fsub_rn(__fadd_rn(qsq, pc.w), __fmul_rn(2.0f, dot));
          bool adm = (d < bd[KNB-1]) || (d == bd[KNB-1] && idx < bi[KNB-1]);
          if (adm){
            #pragma unroll
            for (int p = KNB-1; p >= 1; --p){
              float pd = bd[p-1]; int pi = bi[p-1];
              bool sh  = (pd > d) || (pd == d && pi > idx);
              bool ins = (!sh) && ((bd[p] > d) || (bd[p] == d && bi[p] > idx));
              bd[p] = sh ? pd : (ins ? d   : bd[p]);
              bi[p] = sh ? pi : (ins ? idx : bi[p]);
            }
            bool s0b = (bd[0] > d) || (bd[0] == d && bi[0] > idx);
            if (s0b){ bd[0] = d; bi[0] = idx; }
          }
        }
      }
      if (bd[KNB-1] < 3.0e37f){
        double mg = 1.0e300;
        if (cx - r > 0)      mg = fmin(mg, dqx - (double)(cx-r)*h);
        if (cx + r < GRES-1) mg = fmin(mg, (double)(cx+r+1)*h - dqx);
        if (cy - r > 0)      mg = fmin(mg, dqy - (double)(cy-r)*h);
        if (cy + r < GRES-1) mg = fmin(mg, (double)(cy+r+1)*h - dqy);
        if (cz - r > 0)      mg = fmin(mg, dqz - (double)(cz-r)*h);
        if (cz + r < GRES-1) mg = fmin(mg, (double)(cz+r+1)*h - dqz);
        if (mg*mg > (double)bd[KNB-1] + 1.0e-5) break;
      }
    }
    if (lane < 16) ind_slot[t*KNB + lane] = inv[bi[lane]];
  }
}

// ---------------- proj: q/xk/xv = x@W (bf16 outputs, SLOT order); 64 rows/block ----------------
__global__ __launch_bounds__(256) void proj_kernel(const float* __restrict__ x, const int* __restrict__ pidx,
                                                   const short* __restrict__ pw,
                                                   unsigned short* __restrict__ q, unsigned short* __restrict__ xk,
                                                   unsigned short* __restrict__ xv){
  __shared__ __align__(16) char Abuf[16384];
  int tid = threadIdx.x, lane = tid & 63, wv = tid >> 6;
  int r0 = blockIdx.x * 64;
  {
    int row = tid >> 2, q4 = tid & 3;
    int orig = pidx[r0 + row];
    const float4* xr = (const float4*)(x + (size_t)orig*DIMF + q4*32);
    #pragma unroll
    for (int i=0;i<4;++i){
      float4 a = xr[2*i], b = xr[2*i+1];
      u32x4 u;
      u[0] = cvtpk(a.x, a.y); u[1] = cvtpk(a.z, a.w);
      u[2] = cvtpk(b.x, b.y); u[3] = cvtpk(b.z, b.w);
      *(u32x4*)(&Abuf[row*256 + ((q4*64 + i*16) ^ ((row&7)<<4))]) = u;
    }
  }
  __syncthreads();
  #pragma unroll 1
  for (int w = 0; w < 3; ++w){
    const bf16x8* bw = (const bf16x8*)(pw + w*16384);
    unsigned short* dst = (w==0) ? q : (w==1) ? xk : xv;
    f32x4 acc[8];
    #pragma unroll
    for (int nt=0;nt<8;++nt) acc[nt] = (f32x4){0.f,0.f,0.f,0.f};
    #pragma unroll
    for (int ks=0;ks<4;++ks){
      int ra = wv*16 + (lane&15);
      int cb = ks*64 + ((lane>>4)<<4);
      bf16x8 a0 = *(const bf16x8*)(&Abuf[ra*256 + (cb ^ ((ra&7)<<4))]);
      #pragma unroll
      for (int nt=0;nt<8;++nt){
        bf16x8 b = bw[(nt*4+ks)*64 + lane];
        acc[nt] = __builtin_amdgcn_mfma_f32_16x16x32_bf16(a0, b, acc[nt], 0, 0, 0);
      }
    }
    #pragma unroll
    for (int nt=0;nt<8;++nt){
      int grow = r0 + wv*16 + ((lane>>4)<<2);
      int col = nt*16 + (lane&15);
      unsigned pk01 = cvtpk(acc[nt][0], acc[nt][1]);
      unsigned pk23 = cvtpk(acc[nt][2], acc[nt][3]);
      dst[(size_t)(grow+0)*DIMF + col] = (unsigned short)pk01;
      dst[(size_t)(grow+1)*DIMF + col] = (unsigned short)(pk01 >> 16);
      dst[(size_t)(grow+2)*DIMF + col] = (unsigned short)pk23;
      dst[(size_t)(grow+3)*DIMF + col] = (unsigned short)(pk23 >> 16);
    }
  }
}

// ---------------- fused main kernel: 8 sorted slots / wg, 8 waves, 1 m-tile/wave ----------------
// Proven structure (32KB wbuf full-weight staging, f32 aggT pad-9, fin_w staged) +
// XCD-aware chunked blockIdx swizzle (bijective, nwg%8==0).
__global__ __launch_bounds__(512, 2) void main_kernel(
    const float* __restrict__ x, const float4* __restrict__ pos4, const int* __restrict__ pidx,
    const float* __restrict__ pe_w1, const float* __restrict__ pe_b1, const float* __restrict__ pe_b2,
    const float* __restrict__ mid_b1, const float* __restrict__ mid_b2, const float* __restrict__ fin_b,
    const unsigned short* __restrict__ qarr, const unsigned short* __restrict__ xkarr,
    const unsigned short* __restrict__ xvarr,
    const int* __restrict__ ind_slot, const short* __restrict__ pw,
    float* __restrict__ out)
{
  __shared__ __align__(16) char peLDS[32768];
  __shared__ __align__(16) char wbuf[32768];
  __shared__ float aggT[DIMF][9];     // transposed agg: [col][point], pad 9 (coprime 32 banks)
  __shared__ int indbuf[128];
  __shared__ int origbuf[8];
  int tid = threadIdx.x;
  int lane = tid & 63;
  int wv = tid >> 6;                  // 0..7, owns m-tile mt = wv
  // XCD chunked swizzle (2048 blocks, 8 XCDs, round-robin dispatch assumed; bijective)
  int swz = (blockIdx.x & 7) * (N_PTS/8/8) + (blockIdx.x >> 3);
  int t0 = swz * 8;

  int g = lane >> 4, kl = lane & 15;
  int mt = wv;

  // stage slot's 32KB B-matrix: each wave DMAs its 4KB slice (4 x 1KB, 16B/lane)
  #define STAGE_W(slot) { \
    const char* gsrc = (const char*)(pw + (size_t)(slot)*16384) + wv*4096 + lane*16; \
    char* ldst = &wbuf[wv*4096]; \
    __builtin_amdgcn_global_load_lds(gsrc,        ldst,        16, 0, 0); \
    __builtin_amdgcn_global_load_lds(gsrc + 1024, ldst + 1024, 16, 0, 0); \
    __builtin_amdgcn_global_load_lds(gsrc + 2048, ldst + 2048, 16, 0, 0); \
    __builtin_amdgcn_global_load_lds(gsrc + 3072, ldst + 3072, 16, 0, 0); }

  if (tid < 128) indbuf[tid] = ind_slot[swz*128 + tid];
  if (tid < 8) origbuf[tid] = pidx[t0 + tid];
  STAGE_W(3);                         // pe_w2
  __syncthreads();                    // indbuf + wbuf(pe_w2) ready (vmcnt drained)

  // ---- early-issue z gathers (latency hides under tfrag build + GEMM1) ----
  int nb4[4];
  #pragma unroll
  for (int r=0;r<4;++r) nb4[r] = indbuf[mt*16 + g*4 + r];
  int nbr = indbuf[mt*16 + kl];
  unsigned short zraw[8][4];
  #pragma unroll
  for (int nt=0;nt<8;++nt)
    #pragma unroll
    for (int r=0;r<4;++r)
      zraw[nt][r] = xvarr[(size_t)nb4[r]*DIMF + nt*16 + kl];

  // ---- Phase A: t = relu(rel @ pe_w1 + pe_b1) directly as A-fragments ----
  bf16x8 tfrag[4];
  {
    float4 pq = pos4[t0+mt];
    float4 pn = pos4[nbr];
    float rx = pq.x-pn.x, ry = pq.y-pn.y, rz = pq.z-pn.z;
    #pragma unroll
    for (int ks=0;ks<4;++ks){
      int c0 = ks*32 + g*8;
      const float4* w0 = (const float4*)(pe_w1 + c0);
      const float4* w1 = (const float4*)(pe_w1 + DIMF + c0);
      const float4* w2 = (const float4*)(pe_w1 + 2*DIMF + c0);
      const float4* bb = (const float4*)(pe_b1 + c0);
      float4 wa0=w0[0], wa1=w0[1], wb0=w1[0], wb1=w1[1], wc0=w2[0], wc1=w2[1], wd0=bb[0], wd1=bb[1];
      float wa[8]={wa0.x,wa0.y,wa0.z,wa0.w,wa1.x,wa1.y,wa1.z,wa1.w};
      float wb[8]={wb0.x,wb0.y,wb0.z,wb0.w,wb1.x,wb1.y,wb1.z,wb1.w};
      float wc[8]={wc0.x,wc0.y,wc0.z,wc0.w,wc1.x,wc1.y,wc1.z,wc1.w};
      float wd[8]={wd0.x,wd0.y,wd0.z,wd0.w,wd1.x,wd1.y,wd1.z,wd1.w};
      float tv[8];
      #pragma unroll
      for (int j=0;j<8;++j)
        tv[j] = fmaxf(fmaf(rx, wa[j], fmaf(ry, wb[j], fmaf(rz, wc[j], wd[j]))), 0.f);
      u32x4 u;
      u[0] = cvtpk(tv[0], tv[1]); u[1] = cvtpk(tv[2], tv[3]);
      u[2] = cvtpk(tv[4], tv[5]); u[3] = cvtpk(tv[6], tv[7]);
      tfrag[ks] = __builtin_bit_cast(bf16x8, u);
    }
  }

  f32x4 acc[8];
  const bf16x8* bw = (const bf16x8*)wbuf;

  // ---- GEMM1: pe = t @ pe_w2 + pe_b2 (B from LDS) ----
  {
    #pragma unroll
    for (int nt=0;nt<8;++nt){
      float bv = pe_b2[nt*16 + kl];
      acc[nt] = (f32x4){bv,bv,bv,bv};
    }
    #pragma unroll
    for (int ks=0;ks<4;++ks){
      #pragma unroll
      for (int nt=0;nt<8;++nt){
        bf16x8 b = bw[(nt*4+ks)*64 + lane];
        acc[nt] = __builtin_amdgcn_mfma_f32_16x16x32_bf16(tfrag[ks], b, acc[nt], 0, 0, 0);
      }
    }
  }

  // ---- Epilogue 1: pe -> own LDS slice (bf16, swizzled); z = xv + pe -> bf16 regs ----
  bf16x4 zb[8];
  int r0w = mt*16 + g*4;
  #pragma unroll
  for (int nt=0;nt<8;++nt){
    int col = nt*16 + kl;
    float p0 = acc[nt][0], p1 = acc[nt][1], p2 = acc[nt][2], p3 = acc[nt][3];
    unsigned pk01 = cvtpk(p0, p1), pk23 = cvtpk(p2, p3);
    *(unsigned short*)&peLDS[(r0w+0)*256 + ((col*2) ^ (((r0w+0)&7)<<4))] = (unsigned short)pk01;
    *(unsigned short*)&peLDS[(r0w+1)*256 + ((col*2) ^ (((r0w+1)&7)<<4))] = (unsigned short)(pk01 >> 16);
    *(unsigned short*)&peLDS[(r0w+2)*256 + ((col*2) ^ (((r0w+2)&7)<<4))] = (unsigned short)pk23;
    *(unsigned short*)&peLDS[(r0w+3)*256 + ((col*2) ^ (((r0w+3)&7)<<4))] = (unsigned short)(pk23 >> 16);
    float z0 = b2f(zraw[nt][0]) + p0;
    float z1 = b2f(zraw[nt][1]) + p1;
    float z2 = b2f(zraw[nt][2]) + p2;
    float z3 = b2f(zraw[nt][3]) + p3;
    u32x2 zu; zu[0] = cvtpk(z0, z1); zu[1] = cvtpk(z2, z3);
    zb[nt] = __builtin_bit_cast(bf16x4, zu);
  }

  // q/k A-layout vector gathers
  bf16x8 q8[4], k8[4];
  {
    const unsigned short* qrow = qarr + (size_t)(t0+mt)*DIMF;
    const unsigned short* krow = xkarr + (size_t)nbr*DIMF;
    #pragma unroll
    for (int ks=0;ks<4;++ks){
      int c0 = ks*32 + g*8;
      q8[ks] = *(const bf16x8*)(qrow + c0);
      k8[ks] = *(const bf16x8*)(krow + c0);
    }
  }
  __syncthreads();                    // all GEMM1 wbuf reads done
  STAGE_W(4);                         // mid_w1

  // ---- GEMM2 A-build: h = (q - xk) + pe (own peLDS slice) ----
  bf16x8 hfrag[4];
  {
    int row = mt*16 + kl;
    #pragma unroll
    for (int ks=0;ks<4;++ks){
      int c0 = ks*32 + g*8;
      bf16x8 p8 = *(const bf16x8*)(&peLDS[row*256 + ((c0*2) ^ ((row&7)<<4))]);
      float hf[8];
      #pragma unroll
      for (int j=0;j<8;++j)
        hf[j] = (b2fs(q8[ks][j]) - b2fs(k8[ks][j])) + b2fs(p8[j]);
      u32x4 u;
      u[0] = cvtpk(hf[0], hf[1]); u[1] = cvtpk(hf[2], hf[3]);
      u[2] = cvtpk(hf[4], hf[5]); u[3] = cvtpk(hf[6], hf[7]);
      hfrag[ks] = __builtin_bit_cast(bf16x8, u);
    }
  }
  __syncthreads();                    // wbuf(mid_w1) ready

  // ---- GEMM2: u = relu(h @ mid_w1 + mid_b1) ----
  {
    #pragma unroll
    for (int nt=0;nt<8;++nt){
      float bv = mid_b1[nt*16 + kl];
      acc[nt] = (f32x4){bv,bv,bv,bv};
    }
    #pragma unroll
    for (int ks=0;ks<4;++ks){
      #pragma unroll
      for (int nt=0;nt<8;++nt){
        bf16x8 b = bw[(nt*4+ks)*64 + lane];
        acc[nt] = __builtin_amdgcn_mfma_f32_16x16x32_bf16(hfrag[ks], b, acc[nt], 0, 0, 0);
      }
    }
  }
  __syncthreads();                    // all GEMM2 wbuf reads done
  STAGE_W(5);                         // mid_w2
  // overwrite own slice with u = relu(acc)
  #pragma unroll
  for (int nt=0;nt<8;++nt){
    int col = nt*16 + kl;
    unsigned pk01 = cvtpk(fmaxf(acc[nt][0],0.f), fmaxf(acc[nt][1],0.f));
    unsigned pk23 = cvtpk(fmaxf(acc[nt][2],0.f), fmaxf(acc[nt][3],0.f));
    *(unsigned short*)&peLDS[(r0w+0)*256 + ((col*2) ^ (((r0w+0)&7)<<4))] = (unsigned short)pk01;
    *(unsigned short*)&peLDS[(r0w+1)*256 + ((col*2) ^ (((r0w+1)&7)<<4))] = (unsigned short)(pk01 >> 16);
    *(unsigned short*)&peLDS[(r0w+2)*256 + ((col*2) ^ (((r0w+2)&7)<<4))] = (unsigned short)pk23;
    *(unsigned short*)&peLDS[(r0w+3)*256 + ((col*2) ^ (((r0w+3)&7)<<4))] = (unsigned short)(pk23 >> 16);
  }
  __syncthreads();                    // wbuf(mid_w2) ready

  // ---- GEMM3 MFMA: y = u @ mid_w2 + mid_b2 ----
  {
    #pragma unroll
    for (int nt=0;nt<8;++nt){
      float bv = mid_b2[nt*16 + kl];
      acc[nt] = (f32x4){bv,bv,bv,bv};
    }
    #pragma unroll
    for (int ks=0;ks<4;++ks){
      int ra = mt*16 + kl;
      int cb = ks*64 + g*16;
      bf16x8 a0 = *(const bf16x8*)(&peLDS[ra*256 + (cb ^ ((ra&7)<<4))]);
      #pragma unroll
      for (int nt=0;nt<8;++nt){
        bf16x8 b = bw[(nt*4+ks)*64 + lane];
        acc[nt] = __builtin_amdgcn_mfma_f32_16x16x32_bf16(a0, b, acc[nt], 0, 0, 0);
      }
    }
  }
  __syncthreads();                    // all GEMM3 wbuf reads done
  STAGE_W(6);                         // fin_w DMA overlaps softmax below

  // ---- softmax over K; agg -> aggT (overlapped with fin_w staging) ----
  {
    const float invS = 0.08838834764831843f;   // 1/sqrt(128)
    #pragma unroll
    for (int nt=0;nt<8;++nt){
      f32x4 y = acc[nt];
      float mx = fmaxf(fmaxf(y[0],y[1]), fmaxf(y[2],y[3]));
      mx = fmaxf(mx, __shfl_xor(mx, 16, 64));
      mx = fmaxf(mx, __shfl_xor(mx, 32, 64));
      float e0 = __expf((y[0]-mx)*invS);
      float e1 = __expf((y[1]-mx)*invS);
      float e2 = __expf((y[2]-mx)*invS);
      float e3 = __expf((y[3]-mx)*invS);
      float ssum = e0+e1+e2+e3;
      ssum += __shfl_xor(ssum, 16, 64);
      ssum += __shfl_xor(ssum, 32, 64);
      bf16x4 zv = zb[nt];
      float ps = (e0*b2fs(zv[0]) + e1*b2fs(zv[1]) + e2*b2fs(zv[2]) + e3*b2fs(zv[3])) / ssum;
      ps += __shfl_xor(ps, 16, 64);
      ps += __shfl_xor(ps, 32, 64);
      if (lane < 16) aggT[nt*16 + lane][mt] = ps;
    }
  }
  __syncthreads();                    // wbuf(fin_w) + aggT ready

  // ---- Final via MFMA: out = agg @ fin_w + fin_b + x ; wave wv owns N-tile nt=wv ----
  {
    f32x4 facc = (f32x4){0.f,0.f,0.f,0.f};
    #pragma unroll
    for (int ks=0;ks<4;++ks){
      int c0 = ks*32 + g*8;
      float av[8];
      #pragma unroll
      for (int j=0;j<8;++j)
        av[j] = (kl < 8) ? aggT[c0+j][kl] : 0.f;
      u32x4 u;
      u[0] = cvtpk(av[0], av[1]); u[1] = cvtpk(av[2], av[3]);
      u[2] = cvtpk(av[4], av[5]); u[3] = cvtpk(av[6], av[7]);
      bf16x8 a = __builtin_bit_cast(bf16x8, u);
      bf16x8 b = bw[(wv*4+ks)*64 + lane];
      facc = __builtin_amdgcn_mfma_f32_16x16x32_bf16(a, b, facc, 0, 0, 0);
    }
    int col = wv*16 + kl;
    float fb = fin_b[col];
    if (g < 2){
      #pragma unroll
      for (int r=0;r<4;++r){
        int prow = g*4 + r;
        int o = origbuf[prow];
        out[(size_t)o*DIMF + col] = facc[r] + fb + x[(size_t)o*DIMF + col];
      }
    }
  }
  #undef STAGE_W
}

extern "C" void kernel_launch(void* const* d_in, const int* in_sizes, int n_in,
                              void* d_out, int out_size, void* d_ws, size_t ws_size,
                              hipStream_t stream)
{
  (void)in_sizes; (void)n_in; (void)out_size; (void)ws_size;
  const float* x      = (const float*)d_in[0];
  const float* pos    = (const float*)d_in[1];
  const float* Wq     = (const float*)d_in[2];
  const float* Wk     = (const float*)d_in[3];
  const float* Wv     = (const float*)d_in[4];
  const float* mid_w1 = (const float*)d_in[5];
  const float* mid_b1 = (const float*)d_in[6];
  const float* mid_w2 = (const float*)d_in[7];
  const float* mid_b2 = (const float*)d_in[8];
  const float* pe_w1  = (const float*)d_in[9];
  const float* pe_b1  = (const float*)d_in[10];
  const float* pe_w2  = (const float*)d_in[11];
  const float* pe_b2  = (const float*)d_in[12];
  const float* fin_w  = (const float*)d_in[13];
  const float* fin_b  = (const float*)d_in[14];
  float* out = (float*)d_out;
  char* ws = (char*)d_ws;

  int*    cellcnt = (int*)   (ws + 0);         //  2 KB
  int*    fillp   = (int*)   (ws + 4096);      //  2 KB
  int*    starts  = (int*)   (ws + 8192);      //  2 KB
  int*    pidx    = (int*)   (ws + 49152);     // 64 KB
  float4* pos4    = (float4*)(ws + 114688);    // 256 KB
  int*    ind     = (int*)   (ws + 376832);    //  1 MB (neighbor slots)
  short*  pw      = (short*) (ws + 1425408);   // 224 KB (7 packed 128x128 bf16 weights)
  int*    inv     = (int*)   (ws + 1654784);   // 64 KB
  unsigned short* qarr  = (unsigned short*)(ws + 1720320);   // 4 MB
  unsigned short* xkarr = (unsigned short*)(ws + 5914624);   // 4 MB
  unsigned short* xvarr = (unsigned short*)(ws + 10108928);  // 4 MB (end ~14.3 MB)

  // cooperative build: zero -> count||pack -> scan -> scatter  (one dispatch)
  {
    void* kargs[] = {
      (void*)&pos, (void*)&cellcnt, (void*)&starts, (void*)&fillp,
      (void*)&pos4, (void*)&pidx, (void*)&inv,
      (void*)&Wq, (void*)&Wk, (void*)&Wv, (void*)&pe_w2, (void*)&mid_w1, (void*)&mid_w2, (void*)&fin_w,
      (void*)&pw
    };
    hipLaunchCooperativeKernel((const void*)build_coop, dim3(512), dim3(256), kargs, 0, stream);
  }

  knn_query64 <<<N_PTS/4,  256, 0, stream>>>(pos4, pidx, starts, cellcnt, inv, ind);
  proj_kernel <<<N_PTS/64, 256, 0, stream>>>(x, pidx, pw, qarr, xkarr, xvarr);
  main_kernel <<<N_PTS/8,  512, 0, stream>>>(x, pos4, pidx, pe_w1, pe_b1, pe_b2, mid_b1, mid_b2, fin_b,
                                             qarr, xkarr, xvarr, ind, pw, out);
}

// Round 20
// 163.801 us; speedup vs baseline: 1.9108x; 1.9108x over previous
//
#include <hip/hip_runtime.h>
#include <hip/hip_bf16.h>

#define N_PTS 16384
#define DIMF  128
#define KNB   16
#define GRES  8
#define NCELL (GRES*GRES*GRES)

typedef __attribute__((ext_vector_type(8))) short bf16x8;
typedef __attribute__((ext_vector_type(4))) short bf16x4;
typedef __attribute__((ext_vector_type(4))) float f32x4;
typedef __attribute__((ext_vector_type(4))) unsigned int u32x4;
typedef __attribute__((ext_vector_type(2))) unsigned int u32x2;

__device__ __forceinline__ unsigned short f2b(float f){
  unsigned int u = __float_as_uint(f);
  u = u + 0x7fffu + ((u >> 16) & 1u);
  return (unsigned short)(u >> 16);
}
// packed RNE f32x2 -> bf16x2 (bit-identical to f2b pairs); no builtin on gfx950 -> inline asm
__device__ __forceinline__ unsigned cvtpk(float lo, float hi){
  unsigned r;
  asm("v_cvt_pk_bf16_f32 %0, %1, %2" : "=v"(r) : "v"(lo), "v"(hi));
  return r;
}
__device__ __forceinline__ float b2f(unsigned short u){
  return __uint_as_float(((unsigned)u) << 16);
}
__device__ __forceinline__ float b2fs(short s){
  return __uint_as_float(((unsigned)(unsigned short)s) << 16);
}
__device__ __forceinline__ float unsort_f(unsigned s){
  unsigned u = (s & 0x80000000u) ? (s ^ 0x80000000u) : ~s;
  return __uint_as_float(u);
}

// ---------------- KNN: grid build (GRES=8, 512 cells) ----------------
__global__ __launch_bounds__(256) void count_kernel(const float* __restrict__ pos, int* __restrict__ cnt){
  int i = blockIdx.x*256 + threadIdx.x;
  float px = pos[i*3+0], py = pos[i*3+1], pz = pos[i*3+2];
  int cx = min(GRES-1, max(0,(int)(px*(float)GRES)));
  int cy = min(GRES-1, max(0,(int)(py*(float)GRES)));
  int cz = min(GRES-1, max(0,(int)(pz*(float)GRES)));
  atomicAdd(&cnt[(cz*GRES+cy)*GRES+cx], 1);
}

// parallel exclusive scan of 512 cell counts (2 cells/thread, wave shfl prefix)
__global__ __launch_bounds__(256) void scan_kernel(const int* __restrict__ cnt, int* __restrict__ starts, int* __restrict__ fillp){
  __shared__ int wsum[4];
  int t = threadIdx.x;
  int lane = t & 63, w = t >> 6;
  int a = cnt[2*t], b = cnt[2*t+1];
  int s = a + b;
  int p = s;
  #pragma unroll
  for (int off = 1; off < 64; off <<= 1){
    int v = __shfl_up(p, off, 64);
    if (lane >= off) p += v;
  }
  if (lane == 63) wsum[w] = p;
  __syncthreads();
  int base = 0;
  for (int i = 0; i < w; ++i) base += wsum[i];
  int excl = base + p - s;
  starts[2*t]   = excl;     fillp[2*t]   = excl;
  starts[2*t+1] = excl + a; fillp[2*t+1] = excl + a;
}

// Fused scatter + weight packing (independent given fillp; both low-VGPR).
__global__ __launch_bounds__(256) void scatter_pack(const float* __restrict__ pos, int* __restrict__ fillp,
                                                    float4* __restrict__ pos4, int* __restrict__ pidx,
                                                    int* __restrict__ inv,
                                                    const float* __restrict__ w0, const float* __restrict__ w1,
                                                    const float* __restrict__ w2, const float* __restrict__ w3,
                                                    const float* __restrict__ w4, const float* __restrict__ w5,
                                                    const float* __restrict__ w6,
                                                    short* __restrict__ dst){
  if (blockIdx.x < 64){
    int i = blockIdx.x*256 + threadIdx.x;
    float px = pos[i*3+0], py = pos[i*3+1], pz = pos[i*3+2];
    int cx = min(GRES-1, max(0,(int)(px*(float)GRES)));
    int cy = min(GRES-1, max(0,(int)(py*(float)GRES)));
    int cz = min(GRES-1, max(0,(int)(pz*(float)GRES)));
    int c = (cz*GRES+cy)*GRES+cx;
    float sq = __fadd_rn(__fadd_rn(__fmul_rn(px,px), __fmul_rn(py,py)), __fmul_rn(pz,pz));
    int s = atomicAdd(&fillp[c], 1);
    pos4[s] = make_float4(px, py, pz, sq);
    pidx[s] = i;
    inv[i] = s;
  } else {
    int pb = blockIdx.x - 64;
    int slot = pb >> 6;                         // 64 blocks per weight
    const float* src = (slot==0)?w0:(slot==1)?w1:(slot==2)?w2:(slot==3)?w3:(slot==4)?w4:(slot==5)?w5:w6;
    int f = (pb & 63)*256 + threadIdx.x;        // 0..16383
    int j  = f & 7;
    int ln = (f >> 3) & 63;
    int ks = (f >> 9) & 3;
    int nt = f >> 11;
    int k = ks*32 + ((ln >> 4) << 3) + j;
    int n = nt*16 + (ln & 15);
    dst[slot*16384 + f] = (short)f2b(src[k*DIMF + n]);
  }
}

// One wave per point. Exact top-16 by (d2, idx); d2 replicates numpy f32 bit-exactly.
// tau^2 threshold filter (exact when admitted>=16) + f64 cell-box pruning (cannot change the
// admitted set) -> ballot-compact -> 64-key bitonic. Rare bound failures: inline exact fallback.
__global__ __launch_bounds__(256) void knn_query64(const float4* __restrict__ pos4, const int* __restrict__ pidx,
                                                   const int* __restrict__ starts, const int* __restrict__ cnt,
                                                   const int* __restrict__ inv,
                                                   int* __restrict__ ind_slot){
  __shared__ unsigned long long cand[4][64];
  int lane = threadIdx.x & 63;
  int wv   = threadIdx.x >> 6;
  int t = blockIdx.x*4 + wv;
  float4 qp = pos4[t];
  float qx = qp.x, qy = qp.y, qz = qp.z, qsq = qp.w;
  int cx = min(GRES-1, max(0,(int)(qx*(float)GRES)));
  int cy = min(GRES-1, max(0,(int)(qy*(float)GRES)));
  int cz = min(GRES-1, max(0,(int)(qz*(float)GRES)));
  int zlo = max(0,cz-1), zhi = min(GRES-1,cz+1);
  int ylo = max(0,cy-1), yhi = min(GRES-1,cy+1);
  int xlo = max(0,cx-1), xhi = min(GRES-1,cx+1);
  const double h = 0.125;
  double dqx=(double)qx, dqy=(double)qy, dqz=(double)qz;

  int nb = 0;
  if (lane < 27){
    int dz = lane/9 - 1, dy = (lane/3)%3 - 1, dx = lane%3 - 1;
    int zz = cz+dz, yy = cy+dy, xx = cx+dx;
    if (zz>=zlo && zz<=zhi && yy>=ylo && yy<=yhi && xx>=xlo && xx<=xhi)
      nb = cnt[(zz*GRES+yy)*GRES+xx];
  }
  #pragma unroll
  for (int o=1;o<64;o<<=1) nb += __shfl_xor(nb, o, 64);
  float V = (float)((zhi-zlo+1)*(yhi-ylo+1)*(xhi-xlo+1)) * 0.001953125f;
  float r3 = 3.8197186f * V / (float)nb;
  float tau2 = 2.0f * __powf(r3, 0.66666667f);

  int nfound = 0;
  bool okscan = false;
  for (int it = 0; it < 8; ++it){
    nfound = 0;
    for (int zz=zlo; zz<=zhi; ++zz)
    for (int yy=ylo; yy<=yhi; ++yy)
    for (int xx=xlo; xx<=xhi; ++xx){
      double mdx = fmax(0.0, fmax((double)xx*h - dqx, dqx - (double)(xx+1)*h));
      double mdy = fmax(0.0, fmax((double)yy*h - dqy, dqy - (double)(yy+1)*h));
      double mdz = fmax(0.0, fmax((double)zz*h - dqz, dqz - (double)(zz+1)*h));
      double md2 = mdx*mdx + mdy*mdy + mdz*mdz;
      if (md2 > (double)tau2 + 1.0e-5) continue;
      int c = (zz*GRES+yy)*GRES+xx;
      int s0 = starts[c], n = cnt[c];
      for (int b = 0; b < n; b += 64){
        int o = b + lane;
        bool valid = o < n;
        float d = 3.0e38f; int idx = 0;
        if (valid){
          float4 pc = pos4[s0+o];
          idx = pidx[s0+o];
          float dot = __fmaf_rn(qz, pc.z, __fmaf_rn(qy, pc.y, __fmul_rn(qx, pc.x)));
          d   = __fsub_rn(__fadd_rn(qsq, pc.w), __fmul_rn(2.0f, dot));
        }
        bool admit = valid && (d < tau2);
        unsigned long long mask = __ballot(admit);
        if (admit){
          int pos = nfound + (int)__popcll(mask & ((1ull<<lane)-1ull));
          if (pos < 64){
            unsigned su = __float_as_uint(d);
            su ^= (unsigned)((int)su >> 31) | 0x80000000u;
            cand[wv][pos] = ((unsigned long long)su << 32) | (unsigned)idx;
          }
        }
        nfound += (int)__popcll(mask);
      }
    }
    if (nfound > 64){ tau2 *= 0.7f; continue; }
    if (nfound < 16){ tau2 *= 2.0f; continue; }
    okscan = true; break;
  }

  bool needfb = !okscan;
  if (okscan){
    asm volatile("s_waitcnt lgkmcnt(0)" ::: "memory");
    __builtin_amdgcn_sched_barrier(0);
    unsigned long long key = (lane < nfound) ? cand[wv][lane] : ~0ull;

    #pragma unroll
    for (int k = 2; k <= 64; k <<= 1){
      #pragma unroll
      for (int j = k>>1; j >= 1; j >>= 1){
        unsigned long long other = __shfl_xor(key, j, 64);
        bool takeSmall = (((lane & k) == 0) != ((lane & j) != 0));
        bool less = other < key;
        key = (takeSmall == less) ? other : key;
      }
    }
    if (lane < 16) ind_slot[t*KNB + lane] = inv[(int)(unsigned)(key & 0xffffffffu)];

    unsigned long long k15 = __shfl(key, 15, 64);
    float b16 = unsort_f((unsigned)(k15 >> 32));
    double mg = 1.0e300;
    if (cx-1 > 0)      mg = fmin(mg, dqx - (double)(cx-1)*h);
    if (cx+1 < GRES-1) mg = fmin(mg, (double)(cx+2)*h - dqx);
    if (cy-1 > 0)      mg = fmin(mg, dqy - (double)(cy-1)*h);
    if (cy+1 < GRES-1) mg = fmin(mg, (double)(cy+2)*h - dqy);
    if (cz-1 > 0)      mg = fmin(mg, dqz - (double)(cz-1)*h);
    if (cz+1 < GRES-1) mg = fmin(mg, (double)(cz+2)*h - dqz);
    needfb = !(mg*mg > (double)b16 + 1.0e-5);
  }

  if (needfb){
    float bd[KNB]; int bi[KNB];
    #pragma unroll
    for (int k=0;k<KNB;++k){ bd[k] = 3.0e38f; bi[k] = 0x7fffffff; }
    for (int r = 0; r < GRES; ++r){
      int zl = max(0, cz-r), zh = min(GRES-1, cz+r);
      int yl = max(0, cy-r), yh = min(GRES-1, cy+r);
      int xl = max(0, cx-r), xh = min(GRES-1, cx+r);
      for (int zz = zl; zz <= zh; ++zz)
      for (int yy = yl; yy <= yh; ++yy)
      for (int xx = xl; xx <= xh; ++xx){
        int ring = max(abs(zz-cz), max(abs(yy-cy), abs(xx-cx)));
        if (ring != r) continue;
        int c = (zz*GRES+yy)*GRES+xx;
        int s0 = starts[c], e = s0 + cnt[c];
        for (int s = s0; s < e; ++s){
          float4 pc = pos4[s];
          int idx = pidx[s];
          float dot = __fmaf_rn(qz, pc.z, __fmaf_rn(qy, pc.y, __fmul_rn(qx, pc.x)));
          float d   = __fsub_rn(__fadd_rn(qsq, pc.w), __fmul_rn(2.0f, dot));
          bool adm = (d < bd[KNB-1]) || (d == bd[KNB-1] && idx < bi[KNB-1]);
          if (adm){
            #pragma unroll
            for (int p = KNB-1; p >= 1; --p){
              float pd = bd[p-1]; int pi = bi[p-1];
              bool sh  = (pd > d) || (pd == d && pi > idx);
              bool ins = (!sh) && ((bd[p] > d) || (bd[p] == d && bi[p] > idx));
              bd[p] = sh ? pd : (ins ? d   : bd[p]);
              bi[p] = sh ? pi : (ins ? idx : bi[p]);
            }
            bool s0b = (bd[0] > d) || (bd[0] == d && bi[0] > idx);
            if (s0b){ bd[0] = d; bi[0] = idx; }
          }
        }
      }
      if (bd[KNB-1] < 3.0e37f){
        double mg = 1.0e300;
        if (cx - r > 0)      mg = fmin(mg, dqx - (double)(cx-r)*h);
        if (cx + r < GRES-1) mg = fmin(mg, (double)(cx+r+1)*h - dqx);
        if (cy - r > 0)      mg = fmin(mg, dqy - (double)(cy-r)*h);
        if (cy + r < GRES-1) mg = fmin(mg, (double)(cy+r+1)*h - dqy);
        if (cz - r > 0)      mg = fmin(mg, dqz - (double)(cz-r)*h);
        if (cz + r < GRES-1) mg = fmin(mg, (double)(cz+r+1)*h - dqz);
        if (mg*mg > (double)bd[KNB-1] + 1.0e-5) break;
      }
    }
    if (lane < 16) ind_slot[t*KNB + lane] = inv[bi[lane]];
  }
}

// ---------------- proj: q/xk/xv = x@W (bf16 outputs, SLOT order); 64 rows/block ----------------
__global__ __launch_bounds__(256) void proj_kernel(const float* __restrict__ x, const int* __restrict__ pidx,
                                                   const short* __restrict__ pw,
                                                   unsigned short* __restrict__ q, unsigned short* __restrict__ xk,
                                                   unsigned short* __restrict__ xv){
  __shared__ __align__(16) char Abuf[16384];
  int tid = threadIdx.x, lane = tid & 63, wv = tid >> 6;
  int r0 = blockIdx.x * 64;
  {
    int row = tid >> 2, q4 = tid & 3;
    int orig = pidx[r0 + row];
    const float4* xr = (const float4*)(x + (size_t)orig*DIMF + q4*32);
    #pragma unroll
    for (int i=0;i<4;++i){
      float4 a = xr[2*i], b = xr[2*i+1];
      u32x4 u;
      u[0] = cvtpk(a.x, a.y); u[1] = cvtpk(a.z, a.w);
      u[2] = cvtpk(b.x, b.y); u[3] = cvtpk(b.z, b.w);
      *(u32x4*)(&Abuf[row*256 + ((q4*64 + i*16) ^ ((row&7)<<4))]) = u;
    }
  }
  __syncthreads();
  #pragma unroll 1
  for (int w = 0; w < 3; ++w){
    const bf16x8* bw = (const bf16x8*)(pw + w*16384);
    unsigned short* dst = (w==0) ? q : (w==1) ? xk : xv;
    f32x4 acc[8];
    #pragma unroll
    for (int nt=0;nt<8;++nt) acc[nt] = (f32x4){0.f,0.f,0.f,0.f};
    #pragma unroll
    for (int ks=0;ks<4;++ks){
      int ra = wv*16 + (lane&15);
      int cb = ks*64 + ((lane>>4)<<4);
      bf16x8 a0 = *(const bf16x8*)(&Abuf[ra*256 + (cb ^ ((ra&7)<<4))]);
      #pragma unroll
      for (int nt=0;nt<8;++nt){
        bf16x8 b = bw[(nt*4+ks)*64 + lane];
        acc[nt] = __builtin_amdgcn_mfma_f32_16x16x32_bf16(a0, b, acc[nt], 0, 0, 0);
      }
    }
    #pragma unroll
    for (int nt=0;nt<8;++nt){
      int grow = r0 + wv*16 + ((lane>>4)<<2);
      int col = nt*16 + (lane&15);
      unsigned pk01 = cvtpk(acc[nt][0], acc[nt][1]);
      unsigned pk23 = cvtpk(acc[nt][2], acc[nt][3]);
      dst[(size_t)(grow+0)*DIMF + col] = (unsigned short)pk01;
      dst[(size_t)(grow+1)*DIMF + col] = (unsigned short)(pk01 >> 16);
      dst[(size_t)(grow+2)*DIMF + col] = (unsigned short)pk23;
      dst[(size_t)(grow+3)*DIMF + col] = (unsigned short)(pk23 >> 16);
    }
  }
}

// ---------------- fused main kernel: 8 sorted slots / wg, 8 waves, 1 m-tile/wave ----------------
// Proven structure (32KB wbuf full-weight staging, f32 aggT pad-9, fin_w staged) +
// XCD-aware chunked blockIdx swizzle (bijective, nwg%8==0).
__global__ __launch_bounds__(512, 2) void main_kernel(
    const float* __restrict__ x, const float4* __restrict__ pos4, const int* __restrict__ pidx,
    const float* __restrict__ pe_w1, const float* __restrict__ pe_b1, const float* __restrict__ pe_b2,
    const float* __restrict__ mid_b1, const float* __restrict__ mid_b2, const float* __restrict__ fin_b,
    const unsigned short* __restrict__ qarr, const unsigned short* __restrict__ xkarr,
    const unsigned short* __restrict__ xvarr,
    const int* __restrict__ ind_slot, const short* __restrict__ pw,
    float* __restrict__ out)
{
  __shared__ __align__(16) char peLDS[32768];
  __shared__ __align__(16) char wbuf[32768];
  __shared__ float aggT[DIMF][9];     // transposed agg: [col][point], pad 9 (coprime 32 banks)
  __shared__ int indbuf[128];
  __shared__ int origbuf[8];
  int tid = threadIdx.x;
  int lane = tid & 63;
  int wv = tid >> 6;                  // 0..7, owns m-tile mt = wv
  // XCD chunked swizzle (2048 blocks, 8 XCDs, round-robin dispatch assumed; bijective)
  int swz = (blockIdx.x & 7) * (N_PTS/8/8) + (blockIdx.x >> 3);
  int t0 = swz * 8;

  int g = lane >> 4, kl = lane & 15;
  int mt = wv;

  // stage slot's 32KB B-matrix: each wave DMAs its 4KB slice (4 x 1KB, 16B/lane)
  #define STAGE_W(slot) { \
    const char* gsrc = (const char*)(pw + (size_t)(slot)*16384) + wv*4096 + lane*16; \
    char* ldst = &wbuf[wv*4096]; \
    __builtin_amdgcn_global_load_lds(gsrc,        ldst,        16, 0, 0); \
    __builtin_amdgcn_global_load_lds(gsrc + 1024, ldst + 1024, 16, 0, 0); \
    __builtin_amdgcn_global_load_lds(gsrc + 2048, ldst + 2048, 16, 0, 0); \
    __builtin_amdgcn_global_load_lds(gsrc + 3072, ldst + 3072, 16, 0, 0); }

  if (tid < 128) indbuf[tid] = ind_slot[swz*128 + tid];
  if (tid < 8) origbuf[tid] = pidx[t0 + tid];
  STAGE_W(3);                         // pe_w2
  __syncthreads();                    // indbuf + wbuf(pe_w2) ready (vmcnt drained)

  // ---- early-issue z gathers (latency hides under tfrag build + GEMM1) ----
  int nb4[4];
  #pragma unroll
  for (int r=0;r<4;++r) nb4[r] = indbuf[mt*16 + g*4 + r];
  int nbr = indbuf[mt*16 + kl];
  unsigned short zraw[8][4];
  #pragma unroll
  for (int nt=0;nt<8;++nt)
    #pragma unroll
    for (int r=0;r<4;++r)
      zraw[nt][r] = xvarr[(size_t)nb4[r]*DIMF + nt*16 + kl];

  // ---- Phase A: t = relu(rel @ pe_w1 + pe_b1) directly as A-fragments ----
  bf16x8 tfrag[4];
  {
    float4 pq = pos4[t0+mt];
    float4 pn = pos4[nbr];
    float rx = pq.x-pn.x, ry = pq.y-pn.y, rz = pq.z-pn.z;
    #pragma unroll
    for (int ks=0;ks<4;++ks){
      int c0 = ks*32 + g*8;
      const float4* w0 = (const float4*)(pe_w1 + c0);
      const float4* w1 = (const float4*)(pe_w1 + DIMF + c0);
      const float4* w2 = (const float4*)(pe_w1 + 2*DIMF + c0);
      const float4* bb = (const float4*)(pe_b1 + c0);
      float4 wa0=w0[0], wa1=w0[1], wb0=w1[0], wb1=w1[1], wc0=w2[0], wc1=w2[1], wd0=bb[0], wd1=bb[1];
      float wa[8]={wa0.x,wa0.y,wa0.z,wa0.w,wa1.x,wa1.y,wa1.z,wa1.w};
      float wb[8]={wb0.x,wb0.y,wb0.z,wb0.w,wb1.x,wb1.y,wb1.z,wb1.w};
      float wc[8]={wc0.x,wc0.y,wc0.z,wc0.w,wc1.x,wc1.y,wc1.z,wc1.w};
      float wd[8]={wd0.x,wd0.y,wd0.z,wd0.w,wd1.x,wd1.y,wd1.z,wd1.w};
      float tv[8];
      #pragma unroll
      for (int j=0;j<8;++j)
        tv[j] = fmaxf(fmaf(rx, wa[j], fmaf(ry, wb[j], fmaf(rz, wc[j], wd[j]))), 0.f);
      u32x4 u;
      u[0] = cvtpk(tv[0], tv[1]); u[1] = cvtpk(tv[2], tv[3]);
      u[2] = cvtpk(tv[4], tv[5]); u[3] = cvtpk(tv[6], tv[7]);
      tfrag[ks] = __builtin_bit_cast(bf16x8, u);
    }
  }

  f32x4 acc[8];
  const bf16x8* bw = (const bf16x8*)wbuf;

  // ---- GEMM1: pe = t @ pe_w2 + pe_b2 (B from LDS) ----
  {
    #pragma unroll
    for (int nt=0;nt<8;++nt){
      float bv = pe_b2[nt*16 + kl];
      acc[nt] = (f32x4){bv,bv,bv,bv};
    }
    #pragma unroll
    for (int ks=0;ks<4;++ks){
      #pragma unroll
      for (int nt=0;nt<8;++nt){
        bf16x8 b = bw[(nt*4+ks)*64 + lane];
        acc[nt] = __builtin_amdgcn_mfma_f32_16x16x32_bf16(tfrag[ks], b, acc[nt], 0, 0, 0);
      }
    }
  }

  // ---- Epilogue 1: pe -> own LDS slice (bf16, swizzled); z = xv + pe -> bf16 regs ----
  bf16x4 zb[8];
  int r0w = mt*16 + g*4;
  #pragma unroll
  for (int nt=0;nt<8;++nt){
    int col = nt*16 + kl;
    float p0 = acc[nt][0], p1 = acc[nt][1], p2 = acc[nt][2], p3 = acc[nt][3];
    unsigned pk01 = cvtpk(p0, p1), pk23 = cvtpk(p2, p3);
    *(unsigned short*)&peLDS[(r0w+0)*256 + ((col*2) ^ (((r0w+0)&7)<<4))] = (unsigned short)pk01;
    *(unsigned short*)&peLDS[(r0w+1)*256 + ((col*2) ^ (((r0w+1)&7)<<4))] = (unsigned short)(pk01 >> 16);
    *(unsigned short*)&peLDS[(r0w+2)*256 + ((col*2) ^ (((r0w+2)&7)<<4))] = (unsigned short)pk23;
    *(unsigned short*)&peLDS[(r0w+3)*256 + ((col*2) ^ (((r0w+3)&7)<<4))] = (unsigned short)(pk23 >> 16);
    float z0 = b2f(zraw[nt][0]) + p0;
    float z1 = b2f(zraw[nt][1]) + p1;
    float z2 = b2f(zraw[nt][2]) + p2;
    float z3 = b2f(zraw[nt][3]) + p3;
    u32x2 zu; zu[0] = cvtpk(z0, z1); zu[1] = cvtpk(z2, z3);
    zb[nt] = __builtin_bit_cast(bf16x4, zu);
  }

  // q/k A-layout vector gathers
  bf16x8 q8[4], k8[4];
  {
    const unsigned short* qrow = qarr + (size_t)(t0+mt)*DIMF;
    const unsigned short* krow = xkarr + (size_t)nbr*DIMF;
    #pragma unroll
    for (int ks=0;ks<4;++ks){
      int c0 = ks*32 + g*8;
      q8[ks] = *(const bf16x8*)(qrow + c0);
      k8[ks] = *(const bf16x8*)(krow + c0);
    }
  }
  __syncthreads();                    // all GEMM1 wbuf reads done
  STAGE_W(4);                         // mid_w1

  // ---- GEMM2 A-build: h = (q - xk) + pe (own peLDS slice) ----
  bf16x8 hfrag[4];
  {
    int row = mt*16 + kl;
    #pragma unroll
    for (int ks=0;ks<4;++ks){
      int c0 = ks*32 + g*8;
      bf16x8 p8 = *(const bf16x8*)(&peLDS[row*256 + ((c0*2) ^ ((row&7)<<4))]);
      float hf[8];
      #pragma unroll
      for (int j=0;j<8;++j)
        hf[j] = (b2fs(q8[ks][j]) - b2fs(k8[ks][j])) + b2fs(p8[j]);
      u32x4 u;
      u[0] = cvtpk(hf[0], hf[1]); u[1] = cvtpk(hf[2], hf[3]);
      u[2] = cvtpk(hf[4], hf[5]); u[3] = cvtpk(hf[6], hf[7]);
      hfrag[ks] = __builtin_bit_cast(bf16x8, u);
    }
  }
  __syncthreads();                    // wbuf(mid_w1) ready

  // ---- GEMM2: u = relu(h @ mid_w1 + mid_b1) ----
  {
    #pragma unroll
    for (int nt=0;nt<8;++nt){
      float bv = mid_b1[nt*16 + kl];
      acc[nt] = (f32x4){bv,bv,bv,bv};
    }
    #pragma unroll
    for (int ks=0;ks<4;++ks){
      #pragma unroll
      for (int nt=0;nt<8;++nt){
        bf16x8 b = bw[(nt*4+ks)*64 + lane];
        acc[nt] = __builtin_amdgcn_mfma_f32_16x16x32_bf16(hfrag[ks], b, acc[nt], 0, 0, 0);
      }
    }
  }
  __syncthreads();                    // all GEMM2 wbuf reads done
  STAGE_W(5);                         // mid_w2
  // overwrite own slice with u = relu(acc)
  #pragma unroll
  for (int nt=0;nt<8;++nt){
    int col = nt*16 + kl;
    unsigned pk01 = cvtpk(fmaxf(acc[nt][0],0.f), fmaxf(acc[nt][1],0.f));
    unsigned pk23 = cvtpk(fmaxf(acc[nt][2],0.f), fmaxf(acc[nt][3],0.f));
    *(unsigned short*)&peLDS[(r0w+0)*256 + ((col*2) ^ (((r0w+0)&7)<<4))] = (unsigned short)pk01;
    *(unsigned short*)&peLDS[(r0w+1)*256 + ((col*2) ^ (((r0w+1)&7)<<4))] = (unsigned short)(pk01 >> 16);
    *(unsigned short*)&peLDS[(r0w+2)*256 + ((col*2) ^ (((r0w+2)&7)<<4))] = (unsigned short)pk23;
    *(unsigned short*)&peLDS[(r0w+3)*256 + ((col*2) ^ (((r0w+3)&7)<<4))] = (unsigned short)(pk23 >> 16);
  }
  __syncthreads();                    // wbuf(mid_w2) ready

  // ---- GEMM3 MFMA: y = u @ mid_w2 + mid_b2 ----
  {
    #pragma unroll
    for (int nt=0;nt<8;++nt){
      float bv = mid_b2[nt*16 + kl];
      acc[nt] = (f32x4){bv,bv,bv,bv};
    }
    #pragma unroll
    for (int ks=0;ks<4;++ks){
      int ra = mt*16 + kl;
      int cb = ks*64 + g*16;
      bf16x8 a0 = *(const bf16x8*)(&peLDS[ra*256 + (cb ^ ((ra&7)<<4))]);
      #pragma unroll
      for (int nt=0;nt<8;++nt){
        bf16x8 b = bw[(nt*4+ks)*64 + lane];
        acc[nt] = __builtin_amdgcn_mfma_f32_16x16x32_bf16(a0, b, acc[nt], 0, 0, 0);
      }
    }
  }
  __syncthreads();                    // all GEMM3 wbuf reads done
  STAGE_W(6);                         // fin_w DMA overlaps softmax below

  // ---- softmax over K; agg -> aggT (overlapped with fin_w staging) ----
  {
    const float invS = 0.08838834764831843f;   // 1/sqrt(128)
    #pragma unroll
    for (int nt=0;nt<8;++nt){
      f32x4 y = acc[nt];
      float mx = fmaxf(fmaxf(y[0],y[1]), fmaxf(y[2],y[3]));
      mx = fmaxf(mx, __shfl_xor(mx, 16, 64));
      mx = fmaxf(mx, __shfl_xor(mx, 32, 64));
      float e0 = __expf((y[0]-mx)*invS);
      float e1 = __expf((y[1]-mx)*invS);
      float e2 = __expf((y[2]-mx)*invS);
      float e3 = __expf((y[3]-mx)*invS);
      float ssum = e0+e1+e2+e3;
      ssum += __shfl_xor(ssum, 16, 64);
      ssum += __shfl_xor(ssum, 32, 64);
      bf16x4 zv = zb[nt];
      float ps = (e0*b2fs(zv[0]) + e1*b2fs(zv[1]) + e2*b2fs(zv[2]) + e3*b2fs(zv[3])) / ssum;
      ps += __shfl_xor(ps, 16, 64);
      ps += __shfl_xor(ps, 32, 64);
      if (lane < 16) aggT[nt*16 + lane][mt] = ps;
    }
  }
  __syncthreads();                    // wbuf(fin_w) + aggT ready

  // ---- Final via MFMA: out = agg @ fin_w + fin_b + x ; wave wv owns N-tile nt=wv ----
  {
    f32x4 facc = (f32x4){0.f,0.f,0.f,0.f};
    #pragma unroll
    for (int ks=0;ks<4;++ks){
      int c0 = ks*32 + g*8;
      float av[8];
      #pragma unroll
      for (int j=0;j<8;++j)
        av[j] = (kl < 8) ? aggT[c0+j][kl] : 0.f;
      u32x4 u;
      u[0] = cvtpk(av[0], av[1]); u[1] = cvtpk(av[2], av[3]);
      u[2] = cvtpk(av[4], av[5]); u[3] = cvtpk(av[6], av[7]);
      bf16x8 a = __builtin_bit_cast(bf16x8, u);
      bf16x8 b = bw[(wv*4+ks)*64 + lane];
      facc = __builtin_amdgcn_mfma_f32_16x16x32_bf16(a, b, facc, 0, 0, 0);
    }
    int col = wv*16 + kl;
    float fb = fin_b[col];
    if (g < 2){
      #pragma unroll
      for (int r=0;r<4;++r){
        int prow = g*4 + r;
        int o = origbuf[prow];
        out[(size_t)o*DIMF + col] = facc[r] + fb + x[(size_t)o*DIMF + col];
      }
    }
  }
  #undef STAGE_W
}

extern "C" void kernel_launch(void* const* d_in, const int* in_sizes, int n_in,
                              void* d_out, int out_size, void* d_ws, size_t ws_size,
                              hipStream_t stream)
{
  (void)in_sizes; (void)n_in; (void)out_size; (void)ws_size;
  const float* x      = (const float*)d_in[0];
  const float* pos    = (const float*)d_in[1];
  const float* Wq     = (const float*)d_in[2];
  const float* Wk     = (const float*)d_in[3];
  const float* Wv     = (const float*)d_in[4];
  const float* mid_w1 = (const float*)d_in[5];
  const float* mid_b1 = (const float*)d_in[6];
  const float* mid_w2 = (const float*)d_in[7];
  const float* mid_b2 = (const float*)d_in[8];
  const float* pe_w1  = (const float*)d_in[9];
  const float* pe_b1  = (const float*)d_in[10];
  const float* pe_w2  = (const float*)d_in[11];
  const float* pe_b2  = (const float*)d_in[12];
  const float* fin_w  = (const float*)d_in[13];
  const float* fin_b  = (const float*)d_in[14];
  float* out = (float*)d_out;
  char* ws = (char*)d_ws;

  int*    cellcnt = (int*)   (ws + 0);         //  2 KB
  int*    fillp   = (int*)   (ws + 4096);      //  2 KB
  int*    starts  = (int*)   (ws + 8192);      //  2 KB
  int*    pidx    = (int*)   (ws + 49152);     // 64 KB
  float4* pos4    = (float4*)(ws + 114688);    // 256 KB
  int*    ind     = (int*)   (ws + 376832);    //  1 MB (neighbor slots)
  short*  pw      = (short*) (ws + 1425408);   // 224 KB (7 packed 128x128 bf16 weights)
  int*    inv     = (int*)   (ws + 1654784);   // 64 KB
  unsigned short* qarr  = (unsigned short*)(ws + 1720320);   // 4 MB
  unsigned short* xkarr = (unsigned short*)(ws + 5914624);   // 4 MB
  unsigned short* xvarr = (unsigned short*)(ws + 10108928);  // 4 MB (end ~14.3 MB)

  hipMemsetAsync(cellcnt, 0, NCELL*sizeof(int), stream);
  count_kernel  <<<N_PTS/256, 256, 0, stream>>>(pos, cellcnt);
  scan_kernel   <<<1,         256, 0, stream>>>(cellcnt, starts, fillp);
  scatter_pack  <<<64 + 7*64, 256, 0, stream>>>(pos, fillp, pos4, pidx, inv,
                                                Wq, Wk, Wv, pe_w2, mid_w1, mid_w2, fin_w, pw);
  knn_query64   <<<N_PTS/4,   256, 0, stream>>>(pos4, pidx, starts, cellcnt, inv, ind);
  proj_kernel   <<<N_PTS/64,  256, 0, stream>>>(x, pidx, pw, qarr, xkarr, xvarr);
  main_kernel   <<<N_PTS/8,   512, 0, stream>>>(x, pos4, pidx, pe_w1, pe_b1, pe_b2, mid_b1, mid_b2, fin_b,
                                                qarr, xkarr, xvarr, ind, pw, out);
}

// Round 21
// 157.040 us; speedup vs baseline: 1.9931x; 1.0431x over previous
//
#include <hip/hip_runtime.h>
#include <hip/hip_bf16.h>

#define N_PTS 16384
#define DIMF  128
#define KNB   16
#define GRES  8
#define NCELL (GRES*GRES*GRES)

typedef __attribute__((ext_vector_type(8))) short bf16x8;
typedef __attribute__((ext_vector_type(4))) short bf16x4;
typedef __attribute__((ext_vector_type(4))) float f32x4;
typedef __attribute__((ext_vector_type(4))) unsigned int u32x4;
typedef __attribute__((ext_vector_type(2))) unsigned int u32x2;

__device__ __forceinline__ unsigned short f2b(float f){
  unsigned int u = __float_as_uint(f);
  u = u + 0x7fffu + ((u >> 16) & 1u);
  return (unsigned short)(u >> 16);
}
// packed RNE f32x2 -> bf16x2 (bit-identical to f2b pairs); no builtin on gfx950 -> inline asm
__device__ __forceinline__ unsigned cvtpk(float lo, float hi){
  unsigned r;
  asm("v_cvt_pk_bf16_f32 %0, %1, %2" : "=v"(r) : "v"(lo), "v"(hi));
  return r;
}
__device__ __forceinline__ float b2f(unsigned short u){
  return __uint_as_float(((unsigned)u) << 16);
}
__device__ __forceinline__ float b2fs(short s){
  return __uint_as_float(((unsigned)(unsigned short)s) << 16);
}
__device__ __forceinline__ float unsort_f(unsigned s){
  unsigned u = (s & 0x80000000u) ? (s ^ 0x80000000u) : ~s;
  return __uint_as_float(u);
}

// ---------------- KNN: grid build (GRES=8, 512 cells) ----------------
__global__ __launch_bounds__(256) void count_kernel(const float* __restrict__ pos, int* __restrict__ cnt){
  int i = blockIdx.x*256 + threadIdx.x;
  float px = pos[i*3+0], py = pos[i*3+1], pz = pos[i*3+2];
  int cx = min(GRES-1, max(0,(int)(px*(float)GRES)));
  int cy = min(GRES-1, max(0,(int)(py*(float)GRES)));
  int cz = min(GRES-1, max(0,(int)(pz*(float)GRES)));
  atomicAdd(&cnt[(cz*GRES+cy)*GRES+cx], 1);
}

// parallel exclusive scan of 512 cell counts (2 cells/thread, wave shfl prefix)
__global__ __launch_bounds__(256) void scan_kernel(const int* __restrict__ cnt, int* __restrict__ starts, int* __restrict__ fillp){
  __shared__ int wsum[4];
  int t = threadIdx.x;
  int lane = t & 63, w = t >> 6;
  int a = cnt[2*t], b = cnt[2*t+1];
  int s = a + b;
  int p = s;
  #pragma unroll
  for (int off = 1; off < 64; off <<= 1){
    int v = __shfl_up(p, off, 64);
    if (lane >= off) p += v;
  }
  if (lane == 63) wsum[w] = p;
  __syncthreads();
  int base = 0;
  for (int i = 0; i < w; ++i) base += wsum[i];
  int excl = base + p - s;
  starts[2*t]   = excl;     fillp[2*t]   = excl;
  starts[2*t+1] = excl + a; fillp[2*t+1] = excl + a;
}

// Fused scatter + weight packing (independent given fillp; both low-VGPR).
__global__ __launch_bounds__(256) void scatter_pack(const float* __restrict__ pos, int* __restrict__ fillp,
                                                    float4* __restrict__ pos4, int* __restrict__ pidx,
                                                    int* __restrict__ inv,
                                                    const float* __restrict__ w0, const float* __restrict__ w1,
                                                    const float* __restrict__ w2, const float* __restrict__ w3,
                                                    const float* __restrict__ w4, const float* __restrict__ w5,
                                                    const float* __restrict__ w6,
                                                    short* __restrict__ dst){
  if (blockIdx.x < 64){
    int i = blockIdx.x*256 + threadIdx.x;
    float px = pos[i*3+0], py = pos[i*3+1], pz = pos[i*3+2];
    int cx = min(GRES-1, max(0,(int)(px*(float)GRES)));
    int cy = min(GRES-1, max(0,(int)(py*(float)GRES)));
    int cz = min(GRES-1, max(0,(int)(pz*(float)GRES)));
    int c = (cz*GRES+cy)*GRES+cx;
    float sq = __fadd_rn(__fadd_rn(__fmul_rn(px,px), __fmul_rn(py,py)), __fmul_rn(pz,pz));
    int s = atomicAdd(&fillp[c], 1);
    pos4[s] = make_float4(px, py, pz, sq);
    pidx[s] = i;
    inv[i] = s;
  } else {
    int pb = blockIdx.x - 64;
    int slot = pb >> 6;                         // 64 blocks per weight
    const float* src = (slot==0)?w0:(slot==1)?w1:(slot==2)?w2:(slot==3)?w3:(slot==4)?w4:(slot==5)?w5:w6;
    int f = (pb & 63)*256 + threadIdx.x;        // 0..16383
    int j  = f & 7;
    int ln = (f >> 3) & 63;
    int ks = (f >> 9) & 3;
    int nt = f >> 11;
    int k = ks*32 + ((ln >> 4) << 3) + j;
    int n = nt*16 + (ln & 15);
    dst[slot*16384 + f] = (short)f2b(src[k*DIMF + n]);
  }
}

// One wave per point. Exact top-16 by (d2, idx); d2 replicates numpy f32 bit-exactly.
// tau^2 threshold filter (exact when admitted>=16) + f64 cell-box pruning (cannot change the
// admitted set) -> ballot-compact -> 64-key bitonic. Rare bound failures: inline exact fallback.
__global__ __launch_bounds__(256) void knn_query64(const float4* __restrict__ pos4, const int* __restrict__ pidx,
                                                   const int* __restrict__ starts, const int* __restrict__ cnt,
                                                   const int* __restrict__ inv,
                                                   int* __restrict__ ind_slot){
  __shared__ unsigned long long cand[4][64];
  int lane = threadIdx.x & 63;
  int wv   = threadIdx.x >> 6;
  int t = blockIdx.x*4 + wv;
  float4 qp = pos4[t];
  float qx = qp.x, qy = qp.y, qz = qp.z, qsq = qp.w;
  int cx = min(GRES-1, max(0,(int)(qx*(float)GRES)));
  int cy = min(GRES-1, max(0,(int)(qy*(float)GRES)));
  int cz = min(GRES-1, max(0,(int)(qz*(float)GRES)));
  int zlo = max(0,cz-1), zhi = min(GRES-1,cz+1);
  int ylo = max(0,cy-1), yhi = min(GRES-1,cy+1);
  int xlo = max(0,cx-1), xhi = min(GRES-1,cx+1);
  const double h = 0.125;
  double dqx=(double)qx, dqy=(double)qy, dqz=(double)qz;

  int nb = 0;
  if (lane < 27){
    int dz = lane/9 - 1, dy = (lane/3)%3 - 1, dx = lane%3 - 1;
    int zz = cz+dz, yy = cy+dy, xx = cx+dx;
    if (zz>=zlo && zz<=zhi && yy>=ylo && yy<=yhi && xx>=xlo && xx<=xhi)
      nb = cnt[(zz*GRES+yy)*GRES+xx];
  }
  #pragma unroll
  for (int o=1;o<64;o<<=1) nb += __shfl_xor(nb, o, 64);
  float V = (float)((zhi-zlo+1)*(yhi-ylo+1)*(xhi-xlo+1)) * 0.001953125f;
  float r3 = 3.8197186f * V / (float)nb;
  float tau2 = 2.0f * __powf(r3, 0.66666667f);

  int nfound = 0;
  bool okscan = false;
  for (int it = 0; it < 8; ++it){
    nfound = 0;
    for (int zz=zlo; zz<=zhi; ++zz)
    for (int yy=ylo; yy<=yhi; ++yy)
    for (int xx=xlo; xx<=xhi; ++xx){
      double mdx = fmax(0.0, fmax((double)xx*h - dqx, dqx - (double)(xx+1)*h));
      double mdy = fmax(0.0, fmax((double)yy*h - dqy, dqy - (double)(yy+1)*h));
      double mdz = fmax(0.0, fmax((double)zz*h - dqz, dqz - (double)(zz+1)*h));
      double md2 = mdx*mdx + mdy*mdy + mdz*mdz;
      if (md2 > (double)tau2 + 1.0e-5) continue;
      int c = (zz*GRES+yy)*GRES+xx;
      int s0 = starts[c], n = cnt[c];
      for (int b = 0; b < n; b += 64){
        int o = b + lane;
        bool valid = o < n;
        float d = 3.0e38f; int idx = 0;
        if (valid){
          float4 pc = pos4[s0+o];
          idx = pidx[s0+o];
          float dot = __fmaf_rn(qz, pc.z, __fmaf_rn(qy, pc.y, __fmul_rn(qx, pc.x)));
          d   = __fsub_rn(__fadd_rn(qsq, pc.w), __fmul_rn(2.0f, dot));
        }
        bool admit = valid && (d < tau2);
        unsigned long long mask = __ballot(admit);
        if (admit){
          int pos = nfound + (int)__popcll(mask & ((1ull<<lane)-1ull));
          if (pos < 64){
            unsigned su = __float_as_uint(d);
            su ^= (unsigned)((int)su >> 31) | 0x80000000u;
            cand[wv][pos] = ((unsigned long long)su << 32) | (unsigned)idx;
          }
        }
        nfound += (int)__popcll(mask);
      }
    }
    if (nfound > 64){ tau2 *= 0.7f; continue; }
    if (nfound < 16){ tau2 *= 2.0f; continue; }
    okscan = true; break;
  }

  bool needfb = !okscan;
  if (okscan){
    asm volatile("s_waitcnt lgkmcnt(0)" ::: "memory");
    __builtin_amdgcn_sched_barrier(0);
    unsigned long long key = (lane < nfound) ? cand[wv][lane] : ~0ull;

    #pragma unroll
    for (int k = 2; k <= 64; k <<= 1){
      #pragma unroll
      for (int j = k>>1; j >= 1; j >>= 1){
        unsigned long long other = __shfl_xor(key, j, 64);
        bool takeSmall = (((lane & k) == 0) != ((lane & j) != 0));
        bool less = other < key;
        key = (takeSmall == less) ? other : key;
      }
    }
    if (lane < 16) ind_slot[t*KNB + lane] = inv[(int)(unsigned)(key & 0xffffffffu)];

    unsigned long long k15 = __shfl(key, 15, 64);
    float b16 = unsort_f((unsigned)(k15 >> 32));
    double mg = 1.0e300;
    if (cx-1 > 0)      mg = fmin(mg, dqx - (double)(cx-1)*h);
    if (cx+1 < GRES-1) mg = fmin(mg, (double)(cx+2)*h - dqx);
    if (cy-1 > 0)      mg = fmin(mg, dqy - (double)(cy-1)*h);
    if (cy+1 < GRES-1) mg = fmin(mg, (double)(cy+2)*h - dqy);
    if (cz-1 > 0)      mg = fmin(mg, dqz - (double)(cz-1)*h);
    if (cz+1 < GRES-1) mg = fmin(mg, (double)(cz+2)*h - dqz);
    needfb = !(mg*mg > (double)b16 + 1.0e-5);
  }

  if (needfb){
    float bd[KNB]; int bi[KNB];
    #pragma unroll
    for (int k=0;k<KNB;++k){ bd[k] = 3.0e38f; bi[k] = 0x7fffffff; }
    for (int r = 0; r < GRES; ++r){
      int zl = max(0, cz-r), zh = min(GRES-1, cz+r);
      int yl = max(0, cy-r), yh = min(GRES-1, cy+r);
      int xl = max(0, cx-r), xh = min(GRES-1, cx+r);
      for (int zz = zl; zz <= zh; ++zz)
      for (int yy = yl; yy <= yh; ++yy)
      for (int xx = xl; xx <= xh; ++xx){
        int ring = max(abs(zz-cz), max(abs(yy-cy), abs(xx-cx)));
        if (ring != r) continue;
        int c = (zz*GRES+yy)*GRES+xx;
        int s0 = starts[c], e = s0 + cnt[c];
        for (int s = s0; s < e; ++s){
          float4 pc = pos4[s];
          int idx = pidx[s];
          float dot = __fmaf_rn(qz, pc.z, __fmaf_rn(qy, pc.y, __fmul_rn(qx, pc.x)));
          float d   = __fsub_rn(__fadd_rn(qsq, pc.w), __fmul_rn(2.0f, dot));
          bool adm = (d < bd[KNB-1]) || (d == bd[KNB-1] && idx < bi[KNB-1]);
          if (adm){
            #pragma unroll
            for (int p = KNB-1; p >= 1; --p){
              float pd = bd[p-1]; int pi = bi[p-1];
              bool sh  = (pd > d) || (pd == d && pi > idx);
              bool ins = (!sh) && ((bd[p] > d) || (bd[p] == d && bi[p] > idx));
              bd[p] = sh ? pd : (ins ? d   : bd[p]);
              bi[p] = sh ? pi : (ins ? idx : bi[p]);
            }
            bool s0b = (bd[0] > d) || (bd[0] == d && bi[0] > idx);
            if (s0b){ bd[0] = d; bi[0] = idx; }
          }
        }
      }
      if (bd[KNB-1] < 3.0e37f){
        double mg = 1.0e300;
        if (cx - r > 0)      mg = fmin(mg, dqx - (double)(cx-r)*h);
        if (cx + r < GRES-1) mg = fmin(mg, (double)(cx+r+1)*h - dqx);
        if (cy - r > 0)      mg = fmin(mg, dqy - (double)(cy-r)*h);
        if (cy + r < GRES-1) mg = fmin(mg, (double)(cy+r+1)*h - dqy);
        if (cz - r > 0)      mg = fmin(mg, dqz - (double)(cz-r)*h);
        if (cz + r < GRES-1) mg = fmin(mg, (double)(cz+r+1)*h - dqz);
        if (mg*mg > (double)bd[KNB-1] + 1.0e-5) break;
      }
    }
    if (lane < 16) ind_slot[t*KNB + lane] = inv[bi[lane]];
  }
}

// ---------------- proj: q/xk/xv = x@W (bf16 outputs, SLOT order); 32 rows/block ----------------
// 512 blocks (2 blocks/CU) for latency hiding; wave wv owns (m-tile wv>>1, nt-half wv&1).
// Per-output MFMA chain identical to the 64-row version (same fragments, ascending ks) -> bit-identical.
__global__ __launch_bounds__(256) void proj_kernel(const float* __restrict__ x, const int* __restrict__ pidx,
                                                   const short* __restrict__ pw,
                                                   unsigned short* __restrict__ q, unsigned short* __restrict__ xk,
                                                   unsigned short* __restrict__ xv){
  __shared__ __align__(16) char Abuf[8192];
  int tid = threadIdx.x, lane = tid & 63, wv = tid >> 6;
  int r0 = blockIdx.x * 32;
  {
    int row = tid >> 3, seg = tid & 7;          // 32 rows x 8 segs of 16 cols
    int orig = pidx[r0 + row];
    const float4* xr = (const float4*)(x + (size_t)orig*DIMF + seg*16);
    float4 a = xr[0], b = xr[1], c = xr[2], d = xr[3];
    u32x4 u0, u1;
    u0[0] = cvtpk(a.x, a.y); u0[1] = cvtpk(a.z, a.w);
    u0[2] = cvtpk(b.x, b.y); u0[3] = cvtpk(b.z, b.w);
    u1[0] = cvtpk(c.x, c.y); u1[1] = cvtpk(c.z, c.w);
    u1[2] = cvtpk(d.x, d.y); u1[3] = cvtpk(d.z, d.w);
    *(u32x4*)(&Abuf[row*256 + ((seg*32 +  0) ^ ((row&7)<<4))]) = u0;
    *(u32x4*)(&Abuf[row*256 + ((seg*32 + 16) ^ ((row&7)<<4))]) = u1;
  }
  __syncthreads();
  int mt = wv >> 1;               // 0..1
  int nh = (wv & 1) * 4;          // nt base: 0 or 4
  #pragma unroll 1
  for (int w = 0; w < 3; ++w){
    const bf16x8* bw = (const bf16x8*)(pw + w*16384);
    unsigned short* dst = (w==0) ? q : (w==1) ? xk : xv;
    f32x4 acc[4];
    #pragma unroll
    for (int n=0;n<4;++n) acc[n] = (f32x4){0.f,0.f,0.f,0.f};
    #pragma unroll
    for (int ks=0;ks<4;++ks){
      int ra = mt*16 + (lane&15);
      int cb = ks*64 + ((lane>>4)<<4);
      bf16x8 a0 = *(const bf16x8*)(&Abuf[ra*256 + (cb ^ ((ra&7)<<4))]);
      #pragma unroll
      for (int n=0;n<4;++n){
        bf16x8 b = bw[((nh+n)*4+ks)*64 + lane];
        acc[n] = __builtin_amdgcn_mfma_f32_16x16x32_bf16(a0, b, acc[n], 0, 0, 0);
      }
    }
    #pragma unroll
    for (int n=0;n<4;++n){
      int grow = r0 + mt*16 + ((lane>>4)<<2);
      int col = (nh+n)*16 + (lane&15);
      unsigned pk01 = cvtpk(acc[n][0], acc[n][1]);
      unsigned pk23 = cvtpk(acc[n][2], acc[n][3]);
      dst[(size_t)(grow+0)*DIMF + col] = (unsigned short)pk01;
      dst[(size_t)(grow+1)*DIMF + col] = (unsigned short)(pk01 >> 16);
      dst[(size_t)(grow+2)*DIMF + col] = (unsigned short)pk23;
      dst[(size_t)(grow+3)*DIMF + col] = (unsigned short)(pk23 >> 16);
    }
  }
}

// ---------------- fused main kernel: 8 sorted slots / wg, 8 waves, 1 m-tile/wave ----------------
// Proven structure (32KB wbuf full-weight staging, f32 aggT pad-9, fin_w staged) +
// XCD-aware chunked blockIdx swizzle (bijective, nwg%8==0).
__global__ __launch_bounds__(512, 2) void main_kernel(
    const float* __restrict__ x, const float4* __restrict__ pos4, const int* __restrict__ pidx,
    const float* __restrict__ pe_w1, const float* __restrict__ pe_b1, const float* __restrict__ pe_b2,
    const float* __restrict__ mid_b1, const float* __restrict__ mid_b2, const float* __restrict__ fin_b,
    const unsigned short* __restrict__ qarr, const unsigned short* __restrict__ xkarr,
    const unsigned short* __restrict__ xvarr,
    const int* __restrict__ ind_slot, const short* __restrict__ pw,
    float* __restrict__ out)
{
  __shared__ __align__(16) char peLDS[32768];
  __shared__ __align__(16) char wbuf[32768];
  __shared__ float aggT[DIMF][9];     // transposed agg: [col][point], pad 9 (coprime 32 banks)
  __shared__ int indbuf[128];
  __shared__ int origbuf[8];
  int tid = threadIdx.x;
  int lane = tid & 63;
  int wv = tid >> 6;                  // 0..7, owns m-tile mt = wv
  // XCD chunked swizzle (2048 blocks, 8 XCDs, round-robin dispatch assumed; bijective)
  int swz = (blockIdx.x & 7) * (N_PTS/8/8) + (blockIdx.x >> 3);
  int t0 = swz * 8;

  int g = lane >> 4, kl = lane & 15;
  int mt = wv;

  // stage slot's 32KB B-matrix: each wave DMAs its 4KB slice (4 x 1KB, 16B/lane)
  #define STAGE_W(slot) { \
    const char* gsrc = (const char*)(pw + (size_t)(slot)*16384) + wv*4096 + lane*16; \
    char* ldst = &wbuf[wv*4096]; \
    __builtin_amdgcn_global_load_lds(gsrc,        ldst,        16, 0, 0); \
    __builtin_amdgcn_global_load_lds(gsrc + 1024, ldst + 1024, 16, 0, 0); \
    __builtin_amdgcn_global_load_lds(gsrc + 2048, ldst + 2048, 16, 0, 0); \
    __builtin_amdgcn_global_load_lds(gsrc + 3072, ldst + 3072, 16, 0, 0); }

  if (tid < 128) indbuf[tid] = ind_slot[swz*128 + tid];
  if (tid < 8) origbuf[tid] = pidx[t0 + tid];
  STAGE_W(3);                         // pe_w2
  __syncthreads();                    // indbuf + wbuf(pe_w2) ready (vmcnt drained)

  // ---- early-issue z gathers (latency hides under tfrag build + GEMM1) ----
  int nb4[4];
  #pragma unroll
  for (int r=0;r<4;++r) nb4[r] = indbuf[mt*16 + g*4 + r];
  int nbr = indbuf[mt*16 + kl];
  unsigned short zraw[8][4];
  #pragma unroll
  for (int nt=0;nt<8;++nt)
    #pragma unroll
    for (int r=0;r<4;++r)
      zraw[nt][r] = xvarr[(size_t)nb4[r]*DIMF + nt*16 + kl];

  // ---- Phase A: t = relu(rel @ pe_w1 + pe_b1) directly as A-fragments ----
  bf16x8 tfrag[4];
  {
    float4 pq = pos4[t0+mt];
    float4 pn = pos4[nbr];
    float rx = pq.x-pn.x, ry = pq.y-pn.y, rz = pq.z-pn.z;
    #pragma unroll
    for (int ks=0;ks<4;++ks){
      int c0 = ks*32 + g*8;
      const float4* w0 = (const float4*)(pe_w1 + c0);
      const float4* w1 = (const float4*)(pe_w1 + DIMF + c0);
      const float4* w2 = (const float4*)(pe_w1 + 2*DIMF + c0);
      const float4* bb = (const float4*)(pe_b1 + c0);
      float4 wa0=w0[0], wa1=w0[1], wb0=w1[0], wb1=w1[1], wc0=w2[0], wc1=w2[1], wd0=bb[0], wd1=bb[1];
      float wa[8]={wa0.x,wa0.y,wa0.z,wa0.w,wa1.x,wa1.y,wa1.z,wa1.w};
      float wb[8]={wb0.x,wb0.y,wb0.z,wb0.w,wb1.x,wb1.y,wb1.z,wb1.w};
      float wc[8]={wc0.x,wc0.y,wc0.z,wc0.w,wc1.x,wc1.y,wc1.z,wc1.w};
      float wd[8]={wd0.x,wd0.y,wd0.z,wd0.w,wd1.x,wd1.y,wd1.z,wd1.w};
      float tv[8];
      #pragma unroll
      for (int j=0;j<8;++j)
        tv[j] = fmaxf(fmaf(rx, wa[j], fmaf(ry, wb[j], fmaf(rz, wc[j], wd[j]))), 0.f);
      u32x4 u;
      u[0] = cvtpk(tv[0], tv[1]); u[1] = cvtpk(tv[2], tv[3]);
      u[2] = cvtpk(tv[4], tv[5]); u[3] = cvtpk(tv[6], tv[7]);
      tfrag[ks] = __builtin_bit_cast(bf16x8, u);
    }
  }

  f32x4 acc[8];
  const bf16x8* bw = (const bf16x8*)wbuf;

  // ---- GEMM1: pe = t @ pe_w2 + pe_b2 (B from LDS) ----
  {
    #pragma unroll
    for (int nt=0;nt<8;++nt){
      float bv = pe_b2[nt*16 + kl];
      acc[nt] = (f32x4){bv,bv,bv,bv};
    }
    #pragma unroll
    for (int ks=0;ks<4;++ks){
      #pragma unroll
      for (int nt=0;nt<8;++nt){
        bf16x8 b = bw[(nt*4+ks)*64 + lane];
        acc[nt] = __builtin_amdgcn_mfma_f32_16x16x32_bf16(tfrag[ks], b, acc[nt], 0, 0, 0);
      }
    }
  }

  // ---- Epilogue 1: pe -> own LDS slice (bf16, swizzled); z = xv + pe -> bf16 regs ----
  bf16x4 zb[8];
  int r0w = mt*16 + g*4;
  #pragma unroll
  for (int nt=0;nt<8;++nt){
    int col = nt*16 + kl;
    float p0 = acc[nt][0], p1 = acc[nt][1], p2 = acc[nt][2], p3 = acc[nt][3];
    unsigned pk01 = cvtpk(p0, p1), pk23 = cvtpk(p2, p3);
    *(unsigned short*)&peLDS[(r0w+0)*256 + ((col*2) ^ (((r0w+0)&7)<<4))] = (unsigned short)pk01;
    *(unsigned short*)&peLDS[(r0w+1)*256 + ((col*2) ^ (((r0w+1)&7)<<4))] = (unsigned short)(pk01 >> 16);
    *(unsigned short*)&peLDS[(r0w+2)*256 + ((col*2) ^ (((r0w+2)&7)<<4))] = (unsigned short)pk23;
    *(unsigned short*)&peLDS[(r0w+3)*256 + ((col*2) ^ (((r0w+3)&7)<<4))] = (unsigned short)(pk23 >> 16);
    float z0 = b2f(zraw[nt][0]) + p0;
    float z1 = b2f(zraw[nt][1]) + p1;
    float z2 = b2f(zraw[nt][2]) + p2;
    float z3 = b2f(zraw[nt][3]) + p3;
    u32x2 zu; zu[0] = cvtpk(z0, z1); zu[1] = cvtpk(z2, z3);
    zb[nt] = __builtin_bit_cast(bf16x4, zu);
  }

  // q/k A-layout vector gathers
  bf16x8 q8[4], k8[4];
  {
    const unsigned short* qrow = qarr + (size_t)(t0+mt)*DIMF;
    const unsigned short* krow = xkarr + (size_t)nbr*DIMF;
    #pragma unroll
    for (int ks=0;ks<4;++ks){
      int c0 = ks*32 + g*8;
      q8[ks] = *(const bf16x8*)(qrow + c0);
      k8[ks] = *(const bf16x8*)(krow + c0);
    }
  }
  __syncthreads();                    // all GEMM1 wbuf reads done
  STAGE_W(4);                         // mid_w1

  // ---- GEMM2 A-build: h = (q - xk) + pe (own peLDS slice) ----
  bf16x8 hfrag[4];
  {
    int row = mt*16 + kl;
    #pragma unroll
    for (int ks=0;ks<4;++ks){
      int c0 = ks*32 + g*8;
      bf16x8 p8 = *(const bf16x8*)(&peLDS[row*256 + ((c0*2) ^ ((row&7)<<4))]);
      float hf[8];
      #pragma unroll
      for (int j=0;j<8;++j)
        hf[j] = (b2fs(q8[ks][j]) - b2fs(k8[ks][j])) + b2fs(p8[j]);
      u32x4 u;
      u[0] = cvtpk(hf[0], hf[1]); u[1] = cvtpk(hf[2], hf[3]);
      u[2] = cvtpk(hf[4], hf[5]); u[3] = cvtpk(hf[6], hf[7]);
      hfrag[ks] = __builtin_bit_cast(bf16x8, u);
    }
  }
  __syncthreads();                    // wbuf(mid_w1) ready

  // ---- GEMM2: u = relu(h @ mid_w1 + mid_b1) ----
  {
    #pragma unroll
    for (int nt=0;nt<8;++nt){
      float bv = mid_b1[nt*16 + kl];
      acc[nt] = (f32x4){bv,bv,bv,bv};
    }
    #pragma unroll
    for (int ks=0;ks<4;++ks){
      #pragma unroll
      for (int nt=0;nt<8;++nt){
        bf16x8 b = bw[(nt*4+ks)*64 + lane];
        acc[nt] = __builtin_amdgcn_mfma_f32_16x16x32_bf16(hfrag[ks], b, acc[nt], 0, 0, 0);
      }
    }
  }
  __syncthreads();                    // all GEMM2 wbuf reads done
  STAGE_W(5);                         // mid_w2
  // overwrite own slice with u = relu(acc)
  #pragma unroll
  for (int nt=0;nt<8;++nt){
    int col = nt*16 + kl;
    unsigned pk01 = cvtpk(fmaxf(acc[nt][0],0.f), fmaxf(acc[nt][1],0.f));
    unsigned pk23 = cvtpk(fmaxf(acc[nt][2],0.f), fmaxf(acc[nt][3],0.f));
    *(unsigned short*)&peLDS[(r0w+0)*256 + ((col*2) ^ (((r0w+0)&7)<<4))] = (unsigned short)pk01;
    *(unsigned short*)&peLDS[(r0w+1)*256 + ((col*2) ^ (((r0w+1)&7)<<4))] = (unsigned short)(pk01 >> 16);
    *(unsigned short*)&peLDS[(r0w+2)*256 + ((col*2) ^ (((r0w+2)&7)<<4))] = (unsigned short)pk23;
    *(unsigned short*)&peLDS[(r0w+3)*256 + ((col*2) ^ (((r0w+3)&7)<<4))] = (unsigned short)(pk23 >> 16);
  }
  __syncthreads();                    // wbuf(mid_w2) ready

  // ---- GEMM3 MFMA: y = u @ mid_w2 + mid_b2 ----
  {
    #pragma unroll
    for (int nt=0;nt<8;++nt){
      float bv = mid_b2[nt*16 + kl];
      acc[nt] = (f32x4){bv,bv,bv,bv};
    }
    #pragma unroll
    for (int ks=0;ks<4;++ks){
      int ra = mt*16 + kl;
      int cb = ks*64 + g*16;
      bf16x8 a0 = *(const bf16x8*)(&peLDS[ra*256 + (cb ^ ((ra&7)<<4))]);
      #pragma unroll
      for (int nt=0;nt<8;++nt){
        bf16x8 b = bw[(nt*4+ks)*64 + lane];
        acc[nt] = __builtin_amdgcn_mfma_f32_16x16x32_bf16(a0, b, acc[nt], 0, 0, 0);
      }
    }
  }
  __syncthreads();                    // all GEMM3 wbuf reads done
  STAGE_W(6);                         // fin_w DMA overlaps softmax below

  // ---- softmax over K; agg -> aggT (overlapped with fin_w staging) ----
  {
    const float invS = 0.08838834764831843f;   // 1/sqrt(128)
    #pragma unroll
    for (int nt=0;nt<8;++nt){
      f32x4 y = acc[nt];
      float mx = fmaxf(fmaxf(y[0],y[1]), fmaxf(y[2],y[3]));
      mx = fmaxf(mx, __shfl_xor(mx, 16, 64));
      mx = fmaxf(mx, __shfl_xor(mx, 32, 64));
      float e0 = __expf((y[0]-mx)*invS);
      float e1 = __expf((y[1]-mx)*invS);
      float e2 = __expf((y[2]-mx)*invS);
      float e3 = __expf((y[3]-mx)*invS);
      float ssum = e0+e1+e2+e3;
      ssum += __shfl_xor(ssum, 16, 64);
      ssum += __shfl_xor(ssum, 32, 64);
      bf16x4 zv = zb[nt];
      float ps = (e0*b2fs(zv[0]) + e1*b2fs(zv[1]) + e2*b2fs(zv[2]) + e3*b2fs(zv[3])) / ssum;
      ps += __shfl_xor(ps, 16, 64);
      ps += __shfl_xor(ps, 32, 64);
      if (lane < 16) aggT[nt*16 + lane][mt] = ps;
    }
  }
  __syncthreads();                    // wbuf(fin_w) + aggT ready

  // ---- Final via MFMA: out = agg @ fin_w + fin_b + x ; wave wv owns N-tile nt=wv ----
  {
    f32x4 facc = (f32x4){0.f,0.f,0.f,0.f};
    #pragma unroll
    for (int ks=0;ks<4;++ks){
      int c0 = ks*32 + g*8;
      float av[8];
      #pragma unroll
      for (int j=0;j<8;++j)
        av[j] = (kl < 8) ? aggT[c0+j][kl] : 0.f;
      u32x4 u;
      u[0] = cvtpk(av[0], av[1]); u[1] = cvtpk(av[2], av[3]);
      u[2] = cvtpk(av[4], av[5]); u[3] = cvtpk(av[6], av[7]);
      bf16x8 a = __builtin_bit_cast(bf16x8, u);
      bf16x8 b = bw[(wv*4+ks)*64 + lane];
      facc = __builtin_amdgcn_mfma_f32_16x16x32_bf16(a, b, facc, 0, 0, 0);
    }
    int col = wv*16 + kl;
    float fb = fin_b[col];
    if (g < 2){
      #pragma unroll
      for (int r=0;r<4;++r){
        int prow = g*4 + r;
        int o = origbuf[prow];
        out[(size_t)o*DIMF + col] = facc[r] + fb + x[(size_t)o*DIMF + col];
      }
    }
  }
  #undef STAGE_W
}

extern "C" void kernel_launch(void* const* d_in, const int* in_sizes, int n_in,
                              void* d_out, int out_size, void* d_ws, size_t ws_size,
                              hipStream_t stream)
{
  (void)in_sizes; (void)n_in; (void)out_size; (void)ws_size;
  const float* x      = (const float*)d_in[0];
  const float* pos    = (const float*)d_in[1];
  const float* Wq     = (const float*)d_in[2];
  const float* Wk     = (const float*)d_in[3];
  const float* Wv     = (const float*)d_in[4];
  const float* mid_w1 = (const float*)d_in[5];
  const float* mid_b1 = (const float*)d_in[6];
  const float* mid_w2 = (const float*)d_in[7];
  const float* mid_b2 = (const float*)d_in[8];
  const float* pe_w1  = (const float*)d_in[9];
  const float* pe_b1  = (const float*)d_in[10];
  const float* pe_w2  = (const float*)d_in[11];
  const float* pe_b2  = (const float*)d_in[12];
  const float* fin_w  = (const float*)d_in[13];
  const float* fin_b  = (const float*)d_in[14];
  float* out = (float*)d_out;
  char* ws = (char*)d_ws;

  int*    cellcnt = (int*)   (ws + 0);         //  2 KB
  int*    fillp   = (int*)   (ws + 4096);      //  2 KB
  int*    starts  = (int*)   (ws + 8192);      //  2 KB
  int*    pidx    = (int*)   (ws + 49152);     // 64 KB
  float4* pos4    = (float4*)(ws + 114688);    // 256 KB
  int*    ind     = (int*)   (ws + 376832);    //  1 MB (neighbor slots)
  short*  pw      = (short*) (ws + 1425408);   // 224 KB (7 packed 128x128 bf16 weights)
  int*    inv     = (int*)   (ws + 1654784);   // 64 KB
  unsigned short* qarr  = (unsigned short*)(ws + 1720320);   // 4 MB
  unsigned short* xkarr = (unsigned short*)(ws + 5914624);   // 4 MB
  unsigned short* xvarr = (unsigned short*)(ws + 10108928);  // 4 MB (end ~14.3 MB)

  hipMemsetAsync(cellcnt, 0, NCELL*sizeof(int), stream);
  count_kernel  <<<N_PTS/256, 256, 0, stream>>>(pos, cellcnt);
  scan_kernel   <<<1,         256, 0, stream>>>(cellcnt, starts, fillp);
  scatter_pack  <<<64 + 7*64, 256, 0, stream>>>(pos, fillp, pos4, pidx, inv,
                                                Wq, Wk, Wv, pe_w2, mid_w1, mid_w2, fin_w, pw);
  knn_query64   <<<N_PTS/4,   256, 0, stream>>>(pos4, pidx, starts, cellcnt, inv, ind);
  proj_kernel   <<<N_PTS/32,  256, 0, stream>>>(x, pidx, pw, qarr, xkarr, xvarr);
  main_kernel   <<<N_PTS/8,   512, 0, stream>>>(x, pos4, pidx, pe_w1, pe_b1, pe_b2, mid_b1, mid_b2, fin_b,
                                                qarr, xkarr, xvarr, ind, pw, out);
}